// Round 5
// baseline (520.587 us; speedup 1.0000x reference)
//
#include <hip/hip_runtime.h>

// Problem constants
#define NB   16
#define NQ   300
#define ND   256
#define NH   8
#define NP   4
#define NF   2048
#define NHW  10000
#define NWG  100
#define NROW 4800          // NB*NQ

typedef __attribute__((ext_vector_type(8))) short bf16x8;
typedef __attribute__((ext_vector_type(4))) float f32x4;

__device__ __forceinline__ unsigned short f2bf(float f) {
    unsigned u = __builtin_bit_cast(unsigned, f);
    u = (u + 0x7fffu + ((u >> 16) & 1u)) >> 16;   // RNE
    return (unsigned short)u;
}
__device__ __forceinline__ float bf2f(unsigned short h) {
    unsigned u = ((unsigned)h) << 16;
    return __builtin_bit_cast(float, u);
}

// 8 fp32 -> 8 bf16 (RNE) via packed cvt: 4 VALU instrs instead of ~32.
__device__ __forceinline__ bf16x8 cvt8(float4 lo, float4 hi) {
    unsigned r0, r1, r2, r3;
    asm("v_cvt_pk_bf16_f32 %0, %1, %2" : "=v"(r0) : "v"(lo.x), "v"(lo.y));
    asm("v_cvt_pk_bf16_f32 %0, %1, %2" : "=v"(r1) : "v"(lo.z), "v"(lo.w));
    asm("v_cvt_pk_bf16_f32 %0, %1, %2" : "=v"(r2) : "v"(hi.x), "v"(hi.y));
    asm("v_cvt_pk_bf16_f32 %0, %1, %2" : "=v"(r3) : "v"(hi.z), "v"(hi.w));
    uint4 u = {r0, r1, r2, r3};
    return __builtin_bit_cast(bf16x8, u);
}

// async global->LDS, 16B per lane; LDS dest = wave-uniform base + lane*16
__device__ __forceinline__ void gl_lds16(const unsigned short* g, unsigned short* l) {
    __builtin_amdgcn_global_load_lds(
        (__attribute__((address_space(1))) const void*)g,
        (__attribute__((address_space(3))) void*)l,
        16, 0, 0);
}

// ---------------------------------------------------------------------------
// Tiled transpose+cast: fp32 [K][N] -> bf16 [N][K] for the six GEMM weights.
// ---------------------------------------------------------------------------
__global__ __launch_bounds__(256) void transpose_cast(
    const float* __restrict__ w_in,  const float* __restrict__ w_out,
    const float* __restrict__ w_vp,  const float* __restrict__ w_op,
    const float* __restrict__ w_l1,  const float* __restrict__ w_l2,
    unsigned short* __restrict__ o_in, unsigned short* __restrict__ o_out,
    unsigned short* __restrict__ o_vp, unsigned short* __restrict__ o_op,
    unsigned short* __restrict__ o_l1, unsigned short* __restrict__ o_l2)
{
    __shared__ float ts[64][65];
    int b = blockIdx.x;
    const float* src; unsigned short* dst; int K, N, ncx;
    if      (b < 48)  { src = w_in;  dst = o_in;  K = 256;  N = 768;  ncx = 12; }
    else if (b < 64)  { src = w_out; dst = o_out; K = 256;  N = 256;  ncx = 4;  b -= 48; }
    else if (b < 80)  { src = w_vp;  dst = o_vp;  K = 256;  N = 256;  ncx = 4;  b -= 64; }
    else if (b < 96)  { src = w_op;  dst = o_op;  K = 256;  N = 256;  ncx = 4;  b -= 80; }
    else if (b < 224) { src = w_l1;  dst = o_l1;  K = 256;  N = 2048; ncx = 32; b -= 96; }
    else              { src = w_l2;  dst = o_l2;  K = 2048; N = 256;  ncx = 4;  b -= 224; }
    const int n0 = (b % ncx) * 64, k0 = (b / ncx) * 64;
    const int t = threadIdx.x;
    const int r = t >> 4, c = t & 15;
    #pragma unroll
    for (int j = 0; j < 4; j++) {
        float4 v = *(const float4*)(src + (long)(k0 + j * 16 + r) * N + n0 + c * 4);
        ts[j * 16 + r][c * 4 + 0] = v.x;
        ts[j * 16 + r][c * 4 + 1] = v.y;
        ts[j * 16 + r][c * 4 + 2] = v.z;
        ts[j * 16 + r][c * 4 + 3] = v.w;
    }
    __syncthreads();
    #pragma unroll
    for (int j = 0; j < 4; j++) {
        unsigned short o[4];
        #pragma unroll
        for (int i = 0; i < 4; i++)
            o[i] = f2bf(ts[c * 4 + i][j * 16 + r]);
        *(uint2*)(dst + (long)(n0 + j * 16 + r) * K + k0 + c * 4) = *(uint2*)o;
    }
}

// ---------------------------------------------------------------------------
// Head weights: concat ref/off/attw -> bf16 [128][256] + fp32 bias[128].
// ---------------------------------------------------------------------------
__global__ __launch_bounds__(256) void prep_head(
    const float* __restrict__ rw, const float* __restrict__ rb,
    const float* __restrict__ ow, const float* __restrict__ ob,
    const float* __restrict__ aw, const float* __restrict__ ab,
    unsigned short* __restrict__ o_hd, float* __restrict__ o_hb)
{
    int id = blockIdx.x * 256 + threadIdx.x;
    if (id < 32768) {
        int n = id >> 8, k = id & 255;
        float v;
        if (n < 2)       v = rw[k * 2 + n];
        else if (n < 66) v = ow[k * 64 + (n - 2)];
        else if (n < 98) v = aw[k * 32 + (n - 66)];
        else             v = 0.0f;
        o_hd[id] = f2bf(v);
        return;
    }
    id -= 32768;
    if (id < 128) {
        float v;
        if (id < 2)       v = rb[id];
        else if (id < 66) v = ob[id - 2];
        else if (id < 98) v = ab[id - 66];
        else              v = 0.0f;
        o_hb[id] = v;
    }
}

// ---------------------------------------------------------------------------
// B-STATIONARY vproj GEMM: C[160000,256](bf16) = A(fp32) * Bt[256,256]^T + b.
// The ENTIRE B matrix (256x256 bf16 = 128KB) is staged fragment-linear into
// LDS once (global_load_lds, ONE barrier). After that: zero barriers.
// Grid 250 blocks x 640 rows; 8 waves (2m x 4n); per iter a block streams
// 32 A-rows global->reg (named double-buffer xa/ya, accessed ONLY with
// compile-time indices and never through a pointer parameter -> stays in
// VGPRs), packed-cvt, 32 MFMA/wave against LDS-resident B, stores C.
// Pure HBM-streaming loop; latency hidden by cross-iter ILP + 2 waves/SIMD.
// ---------------------------------------------------------------------------
__global__ __launch_bounds__(512, 2) void gemm_vproj_bs(
    const float* __restrict__ A, const unsigned short* __restrict__ Bt,
    const float* __restrict__ bias, unsigned short* __restrict__ Cout)
{
    // frag(nf,kf) = contiguous 1KB block at shorts [(nf*8+kf)*512], lane-linear
    __shared__ __align__(16) unsigned short Bs[128 * 512];   // 128 KB

    const int t    = threadIdx.x;
    const int wave = t >> 6, lane = t & 63;
    const int l16  = lane & 15, quad = lane >> 4;
    const int wmi  = wave >> 2, wni = wave & 3;   // 2m x 4n
    const long m0  = (long)blockIdx.x * 640;

    // ---- stage all of B: wave stages n-frags 2w, 2w+1 (16 gl_lds) ----
    {
        const unsigned short* bp = Bt + (long)(wave * 32 + l16) * 256 + (quad << 3);
        unsigned short* bw = &Bs[wave << 13];           // (2*wave*8)*512
        #pragma unroll
        for (int kf = 0; kf < 8; kf++) {
            gl_lds16(bp + kf * 32,            bw + kf * 512);
            gl_lds16(bp + kf * 32 + 16 * 256, bw + 4096 + kf * 512);
        }
    }
    __syncthreads();   // the only barrier in this kernel

    float4 bj[4];
    #pragma unroll
    for (int j = 0; j < 4; j++)
        bj[j] = *(const float4*)&bias[wni * 64 + j * 16 + (quad << 2)];

    const float* aBase = A + (m0 + wmi * 16 + l16) * 256L + (quad << 3);

    float4 xa[16], ya[16];   // named A double-buffer (static indices only)

    auto loadX = [&](int it) {
        const float* ap = aBase + (long)it * 32 * 256;
        #pragma unroll
        for (int kf = 0; kf < 8; kf++) {
            xa[2 * kf]     = *(const float4*)(ap + kf * 32);
            xa[2 * kf + 1] = *(const float4*)(ap + kf * 32 + 4);
        }
    };
    auto loadY = [&](int it) {
        const float* ap = aBase + (long)it * 32 * 256;
        #pragma unroll
        for (int kf = 0; kf < 8; kf++) {
            ya[2 * kf]     = *(const float4*)(ap + kf * 32);
            ya[2 * kf + 1] = *(const float4*)(ap + kf * 32 + 4);
        }
    };

    // compute paths reference xa/ya DIRECTLY (no pointer param, no decay):
    auto computeX = [&](int it) {
        f32x4 acc[4] = {};
        #pragma unroll
        for (int kf = 0; kf < 8; kf++) {
            const bf16x8 af = cvt8(xa[2 * kf], xa[2 * kf + 1]);
            #pragma unroll
            for (int j = 0; j < 4; j++) {
                const bf16x8 bv = *(const bf16x8*)
                    &Bs[((wni * 4 + j) * 8 + kf) * 512 + (lane << 3)];
                acc[j] = __builtin_amdgcn_mfma_f32_16x16x32_bf16(
                    bv, af, acc[j], 0, 0, 0);
            }
        }
        const long gr = m0 + it * 32 + wmi * 16 + l16;
        #pragma unroll
        for (int j = 0; j < 4; j++) {
            unsigned short o[4] = {f2bf(acc[j][0] + bj[j].x),
                                   f2bf(acc[j][1] + bj[j].y),
                                   f2bf(acc[j][2] + bj[j].z),
                                   f2bf(acc[j][3] + bj[j].w)};
            const int gc = wni * 64 + j * 16 + (quad << 2);
            *(uint2*)(Cout + gr * 256 + gc) = *(uint2*)o;
        }
    };
    auto computeY = [&](int it) {
        f32x4 acc[4] = {};
        #pragma unroll
        for (int kf = 0; kf < 8; kf++) {
            const bf16x8 af = cvt8(ya[2 * kf], ya[2 * kf + 1]);
            #pragma unroll
            for (int j = 0; j < 4; j++) {
                const bf16x8 bv = *(const bf16x8*)
                    &Bs[((wni * 4 + j) * 8 + kf) * 512 + (lane << 3)];
                acc[j] = __builtin_amdgcn_mfma_f32_16x16x32_bf16(
                    bv, af, acc[j], 0, 0, 0);
            }
        }
        const long gr = m0 + it * 32 + wmi * 16 + l16;
        #pragma unroll
        for (int j = 0; j < 4; j++) {
            unsigned short o[4] = {f2bf(acc[j][0] + bj[j].x),
                                   f2bf(acc[j][1] + bj[j].y),
                                   f2bf(acc[j][2] + bj[j].z),
                                   f2bf(acc[j][3] + bj[j].w)};
            const int gc = wni * 64 + j * 16 + (quad << 2);
            *(uint2*)(Cout + gr * 256 + gc) = *(uint2*)o;
        }
    };

    loadX(0);
    for (int it = 0; it < 20; it += 2) {
        loadY(it + 1);                 // issue next stream while computing
        computeX(it);
        if (it + 2 < 20) loadX(it + 2);
        computeY(it + 1);
    }
}

// ---------------------------------------------------------------------------
// bf16 MFMA GEMM: C[M,N] = A[M,K](fp32) * Bt[N,K](bf16)^T + bias.
// Tile 128 x TN (TN = 128 or 256), 512 threads = 8 waves.
//   TN=256: wave grid 2m x 4n, per-wave 64x64 out, acc[4][4].
//   TN=128: wave grid 4m x 2n, per-wave 32x64 out, acc[2][4].
// Fragment-linear LDS (conflict-free, measured 0), gl_lds B staging,
// reg-staged A (T14). SPLITK>1 writes partial fp32 sums to Cout + z*M*N.
// ---------------------------------------------------------------------------
template <int RELU, int OUTBF, int SPLITK, int TN>
__global__ __launch_bounds__(512, 4) void gemm_bt(
    const float* __restrict__ A, const unsigned short* __restrict__ Bt,
    const float* __restrict__ bias, void* __restrict__ Cout,
    int M, int N, int K)
{
    constexpr int NFB = TN / 16;          // B fragments per K-step (8 or 16)
    constexpr int WN  = TN / 64;          // waves along n (2 or 4)
    constexpr int AI  = WN;               // A-frags per wave (2 or 4)

    __shared__ __align__(16) unsigned short As[2][8 * 512];     // 8KB/buf
    __shared__ __align__(16) unsigned short Bs[2][NFB * 512];   // NFB KB/buf

    const int t    = threadIdx.x;
    const long m0  = (long)blockIdx.y * 128;
    const int  n0  = blockIdx.x * TN;
    const int  wave = t >> 6, lane = t & 63;
    const int  l16 = lane & 15, quad = lane >> 4;
    const int  wmi = wave / WN, wni = wave % WN;
    const int  wm  = wmi * (AI * 16);
    const int  wn  = wni * 64;
    const int  fA  = wmi * AI;
    const int  fB  = wni * 4;

    f32x4 acc[AI][4] = {};

    const int kChunk = K / SPLITK;
    const int kBeg   = (SPLITK > 1) ? blockIdx.z * kChunk : 0;
    const int nk     = kChunk / 32;

    const long aRow   = m0 + wave * 16 + l16;
    const bool aValid = (aRow < M);
    const float* aP   = A + aRow * (long)K + kBeg + (quad << 3);
    unsigned short* aW = &As[0][(wave << 9) + (lane << 3)];   // +buf*4096 shorts

    const unsigned short* bP;
    unsigned short* bW;
    if constexpr (TN == 256) {
        bP = Bt + (long)(n0 + wave * 32 + l16) * K + kBeg + (quad << 3);
        bW = &Bs[0][wave << 10];
    } else {
        bP = Bt + (long)(n0 + wave * 16 + l16) * K + kBeg + (quad << 3);
        bW = &Bs[0][wave << 9];
    }

    float4 la0 = make_float4(0.f, 0.f, 0.f, 0.f);
    float4 la1 = make_float4(0.f, 0.f, 0.f, 0.f);

    auto loadA = [&](int kt) {
        if (aValid) {
            la0 = *(const float4*)(aP + kt * 32);
            la1 = *(const float4*)(aP + kt * 32 + 4);
        }
    };
    auto writeA = [&](int buf) {
        const bf16x8 v = cvt8(la0, la1);
        *(bf16x8*)(aW + buf * 4096) = v;
    };
    auto issueB = [&](int kt, int buf) {
        if constexpr (TN == 256) {
            gl_lds16(bP + kt * 32,                bW + buf * (NFB * 512));
            gl_lds16(bP + kt * 32 + 16 * (long)K, bW + buf * (NFB * 512) + 512);
        } else {
            gl_lds16(bP + kt * 32,                bW + buf * (NFB * 512));
        }
    };

    issueB(0, 0);
    loadA(0);
    writeA(0);
    __syncthreads();

    for (int kt = 0; kt < nk; kt++) {
        const int cur = kt & 1;
        if (kt + 1 < nk) {
            issueB(kt + 1, cur ^ 1);
            loadA(kt + 1);
        }

        bf16x8 af[AI], bfr[4];
        #pragma unroll
        for (int i = 0; i < AI; i++)
            af[i] = *(const bf16x8*)&As[cur][(fA + i) * 512 + (lane << 3)];
        #pragma unroll
        for (int j = 0; j < 4; j++)
            bfr[j] = *(const bf16x8*)&Bs[cur][(fB + j) * 512 + (lane << 3)];
        #pragma unroll
        for (int i = 0; i < AI; i++)
            #pragma unroll
            for (int j = 0; j < 4; j++)
                acc[i][j] = __builtin_amdgcn_mfma_f32_16x16x32_bf16(
                    bfr[j], af[i], acc[i][j], 0, 0, 0);

        if (kt + 1 < nk) {
            writeA(cur ^ 1);
            __syncthreads();
        }
    }

    float4 bj[4];
    #pragma unroll
    for (int j = 0; j < 4; j++)
        bj[j] = *(const float4*)&bias[n0 + wn + j * 16 + (quad << 2)];

    float* outp = (float*)Cout;
    float bscale = 1.0f;
    if (SPLITK > 1) {
        outp += (size_t)blockIdx.z * M * N;        // partial buffer z
        bscale = (blockIdx.z == 0) ? 1.0f : 0.0f;
    }

    #pragma unroll
    for (int i = 0; i < AI; i++) {
        const long gr = m0 + wm + i * 16 + l16;
        if (gr < M) {
            #pragma unroll
            for (int j = 0; j < 4; j++) {
                float4 v;
                v.x = acc[i][j][0] + bscale * bj[j].x;
                v.y = acc[i][j][1] + bscale * bj[j].y;
                v.z = acc[i][j][2] + bscale * bj[j].z;
                v.w = acc[i][j][3] + bscale * bj[j].w;
                if (RELU) {
                    v.x = fmaxf(v.x, 0.f); v.y = fmaxf(v.y, 0.f);
                    v.z = fmaxf(v.z, 0.f); v.w = fmaxf(v.w, 0.f);
                }
                const int gc = n0 + wn + j * 16 + (quad << 2);
                if (OUTBF) {
                    unsigned short o[4] = {f2bf(v.x), f2bf(v.y), f2bf(v.z), f2bf(v.w)};
                    *(uint2*)((unsigned short*)Cout + gr * N + gc) = *(uint2*)o;
                } else {
                    *(float4*)(outp + gr * N + gc) = v;
                }
            }
        }
    }
}

// ---------------------------------------------------------------------------
// MFMA self-attention. Grid (5 q-tiles, 128 b*h).
// ---------------------------------------------------------------------------
__global__ __launch_bounds__(256) void attn_kernel(
    const float* __restrict__ qkv, float* __restrict__ sa)
{
    __shared__ union {
        struct {
            unsigned short Ks[304][40];
            unsigned short Qs[64][40];
        } s;
        unsigned short Ps[4][16][328];
    } u;
    __shared__ unsigned short Vt[32][328];

    const int bh = blockIdx.y;
    const int b  = bh >> 3, h = bh & 7;
    const int q0 = blockIdx.x * 64;
    const int t  = threadIdx.x;

    for (int idx = t; idx < 304 * 8; idx += 256) {
        const int r = idx >> 3, c4 = (idx & 7) << 2;
        if (r < NQ) {
            const float4 kv = *(const float4*)(qkv + ((long)(b * NQ + r)) * 768 + 256 + h * 32 + c4);
            u.s.Ks[r][c4 + 0] = f2bf(kv.x); u.s.Ks[r][c4 + 1] = f2bf(kv.y);
            u.s.Ks[r][c4 + 2] = f2bf(kv.z); u.s.Ks[r][c4 + 3] = f2bf(kv.w);
        } else {
            u.s.Ks[r][c4 + 0] = 0; u.s.Ks[r][c4 + 1] = 0;
            u.s.Ks[r][c4 + 2] = 0; u.s.Ks[r][c4 + 3] = 0;
        }
    }
    for (int idx = t; idx < NQ * 8; idx += 256) {
        const int key = idx >> 3, dq = (idx & 7) << 2;
        const float4 vv = *(const float4*)(qkv + ((long)(b * NQ + key)) * 768 + 512 + h * 32 + dq);
        Vt[dq + 0][key] = f2bf(vv.x); Vt[dq + 1][key] = f2bf(vv.y);
        Vt[dq + 2][key] = f2bf(vv.z); Vt[dq + 3][key] = f2bf(vv.w);
    }
    for (int idx = t; idx < 32 * 20; idx += 256)
        Vt[idx / 20][300 + idx % 20] = 0;
    for (int idx = t; idx < 64 * 8; idx += 256) {
        const int r = idx >> 3, c4 = (idx & 7) << 2;
        const int q = q0 + r;
        if (q < NQ) {
            const float4 qv = *(const float4*)(qkv + ((long)(b * NQ + q)) * 768 + h * 32 + c4);
            u.s.Qs[r][c4 + 0] = f2bf(qv.x); u.s.Qs[r][c4 + 1] = f2bf(qv.y);
            u.s.Qs[r][c4 + 2] = f2bf(qv.z); u.s.Qs[r][c4 + 3] = f2bf(qv.w);
        } else {
            u.s.Qs[r][c4 + 0] = 0; u.s.Qs[r][c4 + 1] = 0;
            u.s.Qs[r][c4 + 2] = 0; u.s.Qs[r][c4 + 3] = 0;
        }
    }
    __syncthreads();

    const int wave = t >> 6, lane = t & 63;
    const int l16 = lane & 15, quad = lane >> 4;
    const float scale = 0.1767766952966369f;

    const bf16x8 aq = *(const bf16x8*)&u.s.Qs[wave * 16 + l16][quad * 8];
    f32x4 sacc[19];
    #pragma unroll
    for (int kt = 0; kt < 19; kt++) {
        const bf16x8 bk = *(const bf16x8*)&u.s.Ks[kt * 16 + l16][quad * 8];
        sacc[kt] = __builtin_amdgcn_mfma_f32_16x16x32_bf16(
            aq, bk, (f32x4){0.f, 0.f, 0.f, 0.f}, 0, 0, 0);
    }

    float inv[4];
    #pragma unroll
    for (int r = 0; r < 4; r++) {
        float m = -1e30f;
        #pragma unroll
        for (int kt = 0; kt < 19; kt++) {
            float s = sacc[kt][r] * scale;
            if (kt == 18 && l16 >= 12) s = -1e30f;
            sacc[kt][r] = s;
            m = fmaxf(m, s);
        }
        m = fmaxf(m, __shfl_xor(m, 1)); m = fmaxf(m, __shfl_xor(m, 2));
        m = fmaxf(m, __shfl_xor(m, 4)); m = fmaxf(m, __shfl_xor(m, 8));
        float sum = 0.f;
        #pragma unroll
        for (int kt = 0; kt < 19; kt++) {
            float p = __expf(sacc[kt][r] - m);
            sacc[kt][r] = p;
            sum += p;
        }
        sum += __shfl_xor(sum, 1); sum += __shfl_xor(sum, 2);
        sum += __shfl_xor(sum, 4); sum += __shfl_xor(sum, 8);
        inv[r] = 1.0f / sum;
    }

    __syncthreads();

    #pragma unroll
    for (int kt = 0; kt < 19; kt++)
        #pragma unroll
        for (int r = 0; r < 4; r++)
            u.Ps[wave][quad * 4 + r][kt * 16 + l16] = f2bf(sacc[kt][r] * inv[r]);
    #pragma unroll
    for (int r = 0; r < 4; r++)
        u.Ps[wave][quad * 4 + r][304 + l16] = 0;

    f32x4 o0 = {0.f, 0.f, 0.f, 0.f}, o1 = {0.f, 0.f, 0.f, 0.f};
    #pragma unroll
    for (int kt = 0; kt < 10; kt++) {
        const bf16x8 ap  = *(const bf16x8*)&u.Ps[wave][l16][kt * 32 + quad * 8];
        const bf16x8 bv0 = *(const bf16x8*)&Vt[l16][kt * 32 + quad * 8];
        const bf16x8 bv1 = *(const bf16x8*)&Vt[16 + l16][kt * 32 + quad * 8];
        o0 = __builtin_amdgcn_mfma_f32_16x16x32_bf16(ap, bv0, o0, 0, 0, 0);
        o1 = __builtin_amdgcn_mfma_f32_16x16x32_bf16(ap, bv1, o1, 0, 0, 0);
    }

    #pragma unroll
    for (int r = 0; r < 4; r++) {
        const int q = q0 + wave * 16 + quad * 4 + r;
        if (q < NQ) {
            float* op = sa + ((long)(b * NQ + q)) * ND + h * 32;
            op[l16]      = o0[r];
            op[16 + l16] = o1[r];
        }
    }
}

// ---------------------------------------------------------------------------
// Residual + LayerNorm (NPART residual partials summed): one wave per row.
// ---------------------------------------------------------------------------
template <int NPART>
__global__ __launch_bounds__(256) void residual_ln(
    const float* __restrict__ a, const float* __restrict__ r,
    const float* __restrict__ gam, const float* __restrict__ bet,
    float* __restrict__ out, long pstride)
{
    const int row  = blockIdx.x * 4 + (threadIdx.x >> 6);
    const int lane = threadIdx.x & 63;
    const long base = (long)row * ND + lane * 4;
    float4 av = *(const float4*)(a + base);
    float4 rv = *(const float4*)(r + base);
    #pragma unroll
    for (int z = 1; z < NPART; z++) {
        float4 pv = *(const float4*)(r + z * pstride + base);
        rv.x += pv.x; rv.y += pv.y; rv.z += pv.z; rv.w += pv.w;
    }
    float x0 = av.x + rv.x, x1 = av.y + rv.y, x2 = av.z + rv.z, x3 = av.w + rv.w;
    float s  = x0 + x1 + x2 + x3;
    float s2 = x0 * x0 + x1 * x1 + x2 * x2 + x3 * x3;
    #pragma unroll
    for (int off = 32; off >= 1; off >>= 1) {
        s  += __shfl_xor(s, off);
        s2 += __shfl_xor(s2, off);
    }
    float mean = s * 0.00390625f;
    float var  = s2 * 0.00390625f - mean * mean;
    float rstd = rsqrtf(var + 1e-5f);
    float4 gv = *(const float4*)(gam + lane * 4);
    float4 bv = *(const float4*)(bet + lane * 4);
    float4 o;
    o.x = (x0 - mean) * rstd * gv.x + bv.x;
    o.y = (x1 - mean) * rstd * gv.y + bv.y;
    o.z = (x2 - mean) * rstd * gv.z + bv.z;
    o.w = (x3 - mean) * rstd * gv.w + bv.w;
    *(float4*)(out + base) = o;
}

// ---------------------------------------------------------------------------
// meta from head-GEMM result res[4800][128].
// ---------------------------------------------------------------------------
__global__ __launch_bounds__(256) void meta_kernel(
    const float* __restrict__ res, float* __restrict__ meta)
{
    const int t   = threadIdx.x;
    const int row = blockIdx.x * 8 + (t >> 5);
    const int s   = t & 31;
    const int h   = s >> 2;
    const float* rp = res + (long)row * 128;
    const float rx = 1.f / (1.f + __expf(-rp[0]));
    const float ry = 1.f / (1.f + __expf(-rp[1]));
    const float offx = rp[2 + 2 * s], offy = rp[3 + 2 * s];
    const float a0 = rp[66 + h * 4 + 0], a1 = rp[66 + h * 4 + 1];
    const float a2 = rp[66 + h * 4 + 2], a3 = rp[66 + h * 4 + 3];
    const float mx = fmaxf(fmaxf(a0, a1), fmaxf(a2, a3));
    const float den = __expf(a0 - mx) + __expf(a1 - mx) +
                      __expf(a2 - mx) + __expf(a3 - mx);
    const float awt = __expf(rp[66 + s] - mx) / den;

    const float lx = fminf(fmaxf(rx + offx, 0.f), 1.f) * (NWG - 1);
    const float ly = fminf(fmaxf(ry + offy, 0.f), 1.f) * (NWG - 1);
    const float fx = floorf(lx), fy = floorf(ly);
    int x0 = (int)fx; x0 = min(max(x0, 0), NWG - 1);
    int y0 = (int)fy; y0 = min(max(y0, 0), NWG - 1);
    const int x1 = min(x0 + 1, NWG - 1);
    const int y1 = min(y0 + 1, NWG - 1);
    const float wx1 = lx - fx, wx0 = 1.f - wx1;
    const float wy1 = ly - fy, wy0 = 1.f - wy1;
    float4 m0, m1;
    m0.x = __int_as_float(y0 * NWG + x0);
    m0.y = __int_as_float(y0 * NWG + x1);
    m0.z = __int_as_float(y1 * NWG + x0);
    m0.w = __int_as_float(y1 * NWG + x1);
    m1.x = awt * wx0 * wy0;
    m1.y = awt * wx1 * wy0;
    m1.z = awt * wx0 * wy1;
    m1.w = awt * wx1 * wy1;
    float* mp = meta + (long)row * 256 + s * 8;
    *(float4*)mp       = m0;
    *(float4*)(mp + 4) = m1;
}

// ---------------------------------------------------------------------------
// Deformable gather: block per (b,q); thread (h = t>>5, d = t&31).
// ---------------------------------------------------------------------------
__global__ __launch_bounds__(256) void deform_gather(
    const float* __restrict__ meta, const unsigned short* __restrict__ vals,
    float* __restrict__ ca)
{
    const int row = blockIdx.x;
    const int b = row / NQ;
    __shared__ float ms[256];
    const int t = threadIdx.x;
    ms[t] = meta[(long)row * 256 + t];
    __syncthreads();
    const int h = t >> 5, d = t & 31;
    const unsigned short* vb = vals + (long)b * NHW * ND + h * 32 + d;
    float acc = 0.f;
    #pragma unroll
    for (int p = 0; p < NP; p++) {
        const float* mp = ms + h * 32 + p * 8;
        const int i00 = __float_as_int(mp[0]);
        const int i01 = __float_as_int(mp[1]);
        const int i10 = __float_as_int(mp[2]);
        const int i11 = __float_as_int(mp[3]);
        acc += mp[4] * bf2f(vb[(long)i00 * ND]);
        acc += mp[5] * bf2f(vb[(long)i01 * ND]);
        acc += mp[6] * bf2f(vb[(long)i10 * ND]);
        acc += mp[7] * bf2f(vb[(long)i11 * ND]);
    }
    ca[(long)row * ND + t] = acc;
}

// ---------------------------------------------------------------------------
extern "C" void kernel_launch(void* const* d_in, const int* in_sizes, int n_in,
                              void* d_out, int out_size, void* d_ws, size_t ws_size,
                              hipStream_t stream)
{
    (void)in_sizes; (void)n_in; (void)out_size; (void)ws_size;
    const float* tgt   = (const float*)d_in[0];
    const float* mem   = (const float*)d_in[1];
    const float* inpw  = (const float*)d_in[2];
    const float* inpb  = (const float*)d_in[3];
    const float* outw  = (const float*)d_in[4];
    const float* outb  = (const float*)d_in[5];
    const float* n1g   = (const float*)d_in[6];
    const float* n1b   = (const float*)d_in[7];
    const float* refw  = (const float*)d_in[8];
    const float* refb  = (const float*)d_in[9];
    const float* offw  = (const float*)d_in[10];
    const float* offb  = (const float*)d_in[11];
    const float* attww = (const float*)d_in[12];
    const float* attwb = (const float*)d_in[13];
    const float* vpw   = (const float*)d_in[14];
    const float* vpb   = (const float*)d_in[15];
    const float* opw   = (const float*)d_in[16];
    const float* opb   = (const float*)d_in[17];
    const float* n2g   = (const float*)d_in[18];
    const float* n2b   = (const float*)d_in[19];
    const float* l1w   = (const float*)d_in[20];
    const float* l1b   = (const float*)d_in[21];
    const float* l2w   = (const float*)d_in[22];
    const float* l2b   = (const float*)d_in[23];
    const float* n3g   = (const float*)d_in[24];
    const float* n3b   = (const float*)d_in[25];
    float* out = (float*)d_out;

    char* p = (char*)d_ws;
    auto alloc = [&](size_t bytes) {
        char* r = p; p += (bytes + 255) & ~(size_t)255; return (void*)r;
    };
    unsigned short* wtIn   = (unsigned short*)alloc(768 * 256 * 2);
    unsigned short* wtOut  = (unsigned short*)alloc(256 * 256 * 2);
    unsigned short* wtVp   = (unsigned short*)alloc(256 * 256 * 2);
    unsigned short* wtOp   = (unsigned short*)alloc(256 * 256 * 2);
    unsigned short* wtL1   = (unsigned short*)alloc(2048 * 256 * 2);
    unsigned short* wtL2   = (unsigned short*)alloc(256 * 2048 * 2);
    unsigned short* wtHead = (unsigned short*)alloc(128 * 256 * 2);
    float*          headb  = (float*)alloc(128 * 4);
    float* qkv  = (float*)alloc((size_t)NROW * 768 * 4);
    float* sa   = (float*)alloc((size_t)NROW * ND * 4);
    float* x1   = (float*)alloc((size_t)NROW * ND * 4);
    float* x2   = (float*)alloc((size_t)NROW * ND * 4);
    float* tmp  = (float*)alloc((size_t)NROW * ND * 4 * 4);   // 4 split-K partials
    float* ca   = (float*)alloc((size_t)NROW * ND * 4);
    float* meta = (float*)alloc((size_t)NROW * 256 * 4);
    void* uni = alloc((size_t)NB * NHW * ND * 2);   // vals bf16 / h1 fp32 alias
    unsigned short* vals = (unsigned short*)uni;
    float* h1 = (float*)uni;
    float* res = qkv;   // head-GEMM result; qkv dead by then

    transpose_cast<<<352, 256, 0, stream>>>(
        inpw, outw, vpw, opw, l1w, l2w,
        wtIn, wtOut, wtVp, wtOp, wtL1, wtL2);
    prep_head<<<129, 256, 0, stream>>>(refw, refb, offw, offb, attww, attwb,
                                       wtHead, headb);

    gemm_bt<0, 0, 1, 256><<<dim3(3, 38), 512, 0, stream>>>(tgt, wtIn, inpb, qkv,
                                                           NROW, 768, 256);
    gemm_vproj_bs<<<250, 512, 0, stream>>>(mem, wtVp, vpb, vals);
    attn_kernel<<<dim3(5, 128), 256, 0, stream>>>(qkv, sa);
    gemm_bt<0, 0, 1, 256><<<dim3(1, 38), 512, 0, stream>>>(sa, wtOut, outb, tmp,
                                                           NROW, 256, 256);
    residual_ln<1><<<1200, 256, 0, stream>>>(tgt, tmp, n1g, n1b, x1, 0);
    gemm_bt<0, 0, 1, 128><<<dim3(1, 38), 512, 0, stream>>>(x1, wtHead, headb, res,
                                                           NROW, 128, 256);
    meta_kernel<<<600, 256, 0, stream>>>(res, meta);
    deform_gather<<<4800, 256, 0, stream>>>(meta, vals, ca);
    gemm_bt<0, 0, 1, 256><<<dim3(1, 38), 512, 0, stream>>>(ca, wtOp, opb, tmp,
                                                           NROW, 256, 256);
    residual_ln<1><<<1200, 256, 0, stream>>>(x1, tmp, n2g, n2b, x2, 0);
    gemm_bt<1, 0, 1, 256><<<dim3(8, 38), 512, 0, stream>>>(x2, wtL1, l1b, h1,
                                                           NROW, 2048, 256);
    gemm_bt<0, 0, 4, 256><<<dim3(1, 38, 4), 512, 0, stream>>>(h1, wtL2, l2b, tmp,
                                                              NROW, 256, 2048);
    residual_ln<4><<<1200, 256, 0, stream>>>(x2, tmp, n3g, n3b, out,
                                             (long)NROW * 256);
}

// Round 6
// 509.106 us; speedup vs baseline: 1.0226x; 1.0226x over previous
//
#include <hip/hip_runtime.h>

// Problem constants
#define NB   16
#define NQ   300
#define ND   256
#define NH   8
#define NP   4
#define NF   2048
#define NHW  10000
#define NWG  100
#define NROW 4800          // NB*NQ

typedef __attribute__((ext_vector_type(8))) short bf16x8;
typedef __attribute__((ext_vector_type(4))) float f32x4;

__device__ __forceinline__ unsigned short f2bf(float f) {
    unsigned u = __builtin_bit_cast(unsigned, f);
    u = (u + 0x7fffu + ((u >> 16) & 1u)) >> 16;   // RNE
    return (unsigned short)u;
}
__device__ __forceinline__ float bf2f(unsigned short h) {
    unsigned u = ((unsigned)h) << 16;
    return __builtin_bit_cast(float, u);
}

// 8 fp32 -> 8 bf16 (RNE) via packed cvt: 4 VALU instrs instead of ~32.
__device__ __forceinline__ bf16x8 cvt8(float4 lo, float4 hi) {
    unsigned r0, r1, r2, r3;
    asm("v_cvt_pk_bf16_f32 %0, %1, %2" : "=v"(r0) : "v"(lo.x), "v"(lo.y));
    asm("v_cvt_pk_bf16_f32 %0, %1, %2" : "=v"(r1) : "v"(lo.z), "v"(lo.w));
    asm("v_cvt_pk_bf16_f32 %0, %1, %2" : "=v"(r2) : "v"(hi.x), "v"(hi.y));
    asm("v_cvt_pk_bf16_f32 %0, %1, %2" : "=v"(r3) : "v"(hi.z), "v"(hi.w));
    uint4 u = {r0, r1, r2, r3};
    return __builtin_bit_cast(bf16x8, u);
}

// async global->LDS, 16B per lane; LDS dest = wave-uniform base + lane*16
__device__ __forceinline__ void gl_lds16(const unsigned short* g, unsigned short* l) {
    __builtin_amdgcn_global_load_lds(
        (__attribute__((address_space(1))) const void*)g,
        (__attribute__((address_space(3))) void*)l,
        16, 0, 0);
}

// ---------------------------------------------------------------------------
// Tiled transpose+cast: fp32 [K][N] -> bf16 [N][K] for the six GEMM weights.
// ---------------------------------------------------------------------------
__global__ __launch_bounds__(256) void transpose_cast(
    const float* __restrict__ w_in,  const float* __restrict__ w_out,
    const float* __restrict__ w_vp,  const float* __restrict__ w_op,
    const float* __restrict__ w_l1,  const float* __restrict__ w_l2,
    unsigned short* __restrict__ o_in, unsigned short* __restrict__ o_out,
    unsigned short* __restrict__ o_vp, unsigned short* __restrict__ o_op,
    unsigned short* __restrict__ o_l1, unsigned short* __restrict__ o_l2)
{
    __shared__ float ts[64][65];
    int b = blockIdx.x;
    const float* src; unsigned short* dst; int K, N, ncx;
    if      (b < 48)  { src = w_in;  dst = o_in;  K = 256;  N = 768;  ncx = 12; }
    else if (b < 64)  { src = w_out; dst = o_out; K = 256;  N = 256;  ncx = 4;  b -= 48; }
    else if (b < 80)  { src = w_vp;  dst = o_vp;  K = 256;  N = 256;  ncx = 4;  b -= 64; }
    else if (b < 96)  { src = w_op;  dst = o_op;  K = 256;  N = 256;  ncx = 4;  b -= 80; }
    else if (b < 224) { src = w_l1;  dst = o_l1;  K = 256;  N = 2048; ncx = 32; b -= 96; }
    else              { src = w_l2;  dst = o_l2;  K = 2048; N = 256;  ncx = 4;  b -= 224; }
    const int n0 = (b % ncx) * 64, k0 = (b / ncx) * 64;
    const int t = threadIdx.x;
    const int r = t >> 4, c = t & 15;
    #pragma unroll
    for (int j = 0; j < 4; j++) {
        float4 v = *(const float4*)(src + (long)(k0 + j * 16 + r) * N + n0 + c * 4);
        ts[j * 16 + r][c * 4 + 0] = v.x;
        ts[j * 16 + r][c * 4 + 1] = v.y;
        ts[j * 16 + r][c * 4 + 2] = v.z;
        ts[j * 16 + r][c * 4 + 3] = v.w;
    }
    __syncthreads();
    #pragma unroll
    for (int j = 0; j < 4; j++) {
        unsigned short o[4];
        #pragma unroll
        for (int i = 0; i < 4; i++)
            o[i] = f2bf(ts[c * 4 + i][j * 16 + r]);
        *(uint2*)(dst + (long)(n0 + j * 16 + r) * K + k0 + c * 4) = *(uint2*)o;
    }
}

// ---------------------------------------------------------------------------
// Head weights: concat ref/off/attw -> bf16 [128][256] + fp32 bias[128].
// ---------------------------------------------------------------------------
__global__ __launch_bounds__(256) void prep_head(
    const float* __restrict__ rw, const float* __restrict__ rb,
    const float* __restrict__ ow, const float* __restrict__ ob,
    const float* __restrict__ aw, const float* __restrict__ ab,
    unsigned short* __restrict__ o_hd, float* __restrict__ o_hb)
{
    int id = blockIdx.x * 256 + threadIdx.x;
    if (id < 32768) {
        int n = id >> 8, k = id & 255;
        float v;
        if (n < 2)       v = rw[k * 2 + n];
        else if (n < 66) v = ow[k * 64 + (n - 2)];
        else if (n < 98) v = aw[k * 32 + (n - 66)];
        else             v = 0.0f;
        o_hd[id] = f2bf(v);
        return;
    }
    id -= 32768;
    if (id < 128) {
        float v;
        if (id < 2)       v = rb[id];
        else if (id < 66) v = ob[id - 2];
        else if (id < 98) v = ab[id - 66];
        else              v = 0.0f;
        o_hb[id] = v;
    }
}

// ---------------------------------------------------------------------------
// B-STATIONARY vproj GEMM: C[160000,256](bf16) = A(fp32) * Bt[256,256]^T + b.
// Entire B (128KB bf16) staged fragment-linear in LDS once; ONE barrier.
// 250 blocks x 640 rows; 8 waves (2m x 4n). Per iter each wave streams its
// A row-slice global->reg into NAMED float4 registers (x0..x15 / y0..y15 —
// arrays, even statically indexed, get demoted to scratch by this toolchain:
// r4/r5 measured VGPR=96 < the 128 the buffers need). sched_barrier(0) after
// each load cluster pins the prefetch issue point (prevents scheduler
// sinking loads to uses, the r2 failure). Zero barriers in the loop.
// ---------------------------------------------------------------------------
#define VLD(V, ap)                                  \
    V##0  = *(const float4*)((ap));                 \
    V##1  = *(const float4*)((ap) + 4);             \
    V##2  = *(const float4*)((ap) + 32);            \
    V##3  = *(const float4*)((ap) + 36);            \
    V##4  = *(const float4*)((ap) + 64);            \
    V##5  = *(const float4*)((ap) + 68);            \
    V##6  = *(const float4*)((ap) + 96);            \
    V##7  = *(const float4*)((ap) + 100);           \
    V##8  = *(const float4*)((ap) + 128);           \
    V##9  = *(const float4*)((ap) + 132);           \
    V##10 = *(const float4*)((ap) + 160);           \
    V##11 = *(const float4*)((ap) + 164);           \
    V##12 = *(const float4*)((ap) + 192);           \
    V##13 = *(const float4*)((ap) + 196);           \
    V##14 = *(const float4*)((ap) + 224);           \
    V##15 = *(const float4*)((ap) + 228);

#define VKF(V, a, b, kf)                                                      \
    {   const bf16x8 af = cvt8(V##a, V##b);                                   \
        const bf16x8 bv0 = *(const bf16x8*)(bsBase + (0 * 8 + kf) * 512);     \
        const bf16x8 bv1 = *(const bf16x8*)(bsBase + (1 * 8 + kf) * 512);     \
        const bf16x8 bv2 = *(const bf16x8*)(bsBase + (2 * 8 + kf) * 512);     \
        const bf16x8 bv3 = *(const bf16x8*)(bsBase + (3 * 8 + kf) * 512);     \
        acc0 = __builtin_amdgcn_mfma_f32_16x16x32_bf16(bv0, af, acc0, 0, 0, 0); \
        acc1 = __builtin_amdgcn_mfma_f32_16x16x32_bf16(bv1, af, acc1, 0, 0, 0); \
        acc2 = __builtin_amdgcn_mfma_f32_16x16x32_bf16(bv2, af, acc2, 0, 0, 0); \
        acc3 = __builtin_amdgcn_mfma_f32_16x16x32_bf16(bv3, af, acc3, 0, 0, 0); }

#define STORE1(acc, bj, off)                                                  \
    {   unsigned short o[4] = {f2bf(acc[0] + bj.x), f2bf(acc[1] + bj.y),      \
                               f2bf(acc[2] + bj.z), f2bf(acc[3] + bj.w)};     \
        *(uint2*)(cp + (off)) = *(uint2*)o; }

#define VCOMP(V, it)                                                          \
    {   f32x4 acc0 = {0.f, 0.f, 0.f, 0.f}, acc1 = {0.f, 0.f, 0.f, 0.f};      \
        f32x4 acc2 = {0.f, 0.f, 0.f, 0.f}, acc3 = {0.f, 0.f, 0.f, 0.f};      \
        VKF(V, 0, 1, 0)   VKF(V, 2, 3, 1)   VKF(V, 4, 5, 2)   VKF(V, 6, 7, 3) \
        VKF(V, 8, 9, 4)   VKF(V, 10, 11, 5) VKF(V, 12, 13, 6) VKF(V, 14, 15, 7) \
        const long gr = m0 + (long)(it) * 32 + wmi * 16 + l16;                \
        unsigned short* cp = Cout + gr * 256 + wni * 64 + (quad << 2);        \
        STORE1(acc0, bj0, 0)  STORE1(acc1, bj1, 16)                           \
        STORE1(acc2, bj2, 32) STORE1(acc3, bj3, 48) }

__global__ __launch_bounds__(512, 2) void gemm_vproj_bs(
    const float* __restrict__ A, const unsigned short* __restrict__ Bt,
    const float* __restrict__ bias, unsigned short* __restrict__ Cout)
{
    // frag(nf,kf) = contiguous 1KB block at shorts [(nf*8+kf)*512], lane-linear
    __shared__ __align__(16) unsigned short Bs[128 * 512];   // 128 KB

    const int t    = threadIdx.x;
    const int wave = t >> 6, lane = t & 63;
    const int l16  = lane & 15, quad = lane >> 4;
    const int wmi  = wave >> 2, wni = wave & 3;   // 2m x 4n
    const long m0  = (long)blockIdx.x * 640;

    // ---- stage all of B: wave stages n-frags 2w, 2w+1 (16 gl_lds) ----
    {
        const unsigned short* bp = Bt + (long)(wave * 32 + l16) * 256 + (quad << 3);
        unsigned short* bw = &Bs[wave << 13];           // (2*wave*8)*512
        #pragma unroll
        for (int kf = 0; kf < 8; kf++) {
            gl_lds16(bp + kf * 32,            bw + kf * 512);
            gl_lds16(bp + kf * 32 + 16 * 256, bw + 4096 + kf * 512);
        }
    }
    __syncthreads();   // the only barrier in this kernel

    float4 bj0 = *(const float4*)&bias[wni * 64 +  0 + (quad << 2)];
    float4 bj1 = *(const float4*)&bias[wni * 64 + 16 + (quad << 2)];
    float4 bj2 = *(const float4*)&bias[wni * 64 + 32 + (quad << 2)];
    float4 bj3 = *(const float4*)&bias[wni * 64 + 48 + (quad << 2)];

    const float* aBase = A + (m0 + wmi * 16 + l16) * 256L + (quad << 3);
    const unsigned short* bsBase = &Bs[(wni * 32) * 512 + (lane << 3)];

    float4 x0, x1, x2, x3, x4, x5, x6, x7, x8, x9, x10, x11, x12, x13, x14, x15;
    float4 y0, y1, y2, y3, y4, y5, y6, y7, y8, y9, y10, y11, y12, y13, y14, y15;

    VLD(x, aBase)
    __builtin_amdgcn_sched_barrier(0);
    for (int it = 0; it < 20; it += 2) {
        const float* apY = aBase + (long)(it + 1) * 8192;
        VLD(y, apY)
        __builtin_amdgcn_sched_barrier(0);   // pin: Y loads issued before X compute
        VCOMP(x, it)
        if (it + 2 < 20) {
            const float* apX = aBase + (long)(it + 2) * 8192;
            VLD(x, apX)
            __builtin_amdgcn_sched_barrier(0);   // pin: X loads before Y compute
        }
        VCOMP(y, it + 1)
    }
}

// ---------------------------------------------------------------------------
// bf16 MFMA GEMM: C[M,N] = A[M,K](fp32) * Bt[N,K](bf16)^T + bias.
// Tile 128 x TN (TN = 128 or 256), 512 threads = 8 waves.
// Fragment-linear LDS (conflict-free, measured 0), gl_lds B staging,
// reg-staged A (T14). SPLITK>1 writes partial fp32 sums to Cout + z*M*N.
// ---------------------------------------------------------------------------
template <int RELU, int OUTBF, int SPLITK, int TN>
__global__ __launch_bounds__(512, 4) void gemm_bt(
    const float* __restrict__ A, const unsigned short* __restrict__ Bt,
    const float* __restrict__ bias, void* __restrict__ Cout,
    int M, int N, int K)
{
    constexpr int NFB = TN / 16;          // B fragments per K-step (8 or 16)
    constexpr int WN  = TN / 64;          // waves along n (2 or 4)
    constexpr int AI  = WN;               // A-frags per wave (2 or 4)

    __shared__ __align__(16) unsigned short As[2][8 * 512];     // 8KB/buf
    __shared__ __align__(16) unsigned short Bs[2][NFB * 512];   // NFB KB/buf

    const int t    = threadIdx.x;
    const long m0  = (long)blockIdx.y * 128;
    const int  n0  = blockIdx.x * TN;
    const int  wave = t >> 6, lane = t & 63;
    const int  l16 = lane & 15, quad = lane >> 4;
    const int  wmi = wave / WN, wni = wave % WN;
    const int  wm  = wmi * (AI * 16);
    const int  wn  = wni * 64;
    const int  fA  = wmi * AI;
    const int  fB  = wni * 4;

    f32x4 acc[AI][4] = {};

    const int kChunk = K / SPLITK;
    const int kBeg   = (SPLITK > 1) ? blockIdx.z * kChunk : 0;
    const int nk     = kChunk / 32;

    const long aRow   = m0 + wave * 16 + l16;
    const bool aValid = (aRow < M);
    const float* aP   = A + aRow * (long)K + kBeg + (quad << 3);
    unsigned short* aW = &As[0][(wave << 9) + (lane << 3)];   // +buf*4096 shorts

    const unsigned short* bP;
    unsigned short* bW;
    if constexpr (TN == 256) {
        bP = Bt + (long)(n0 + wave * 32 + l16) * K + kBeg + (quad << 3);
        bW = &Bs[0][wave << 10];
    } else {
        bP = Bt + (long)(n0 + wave * 16 + l16) * K + kBeg + (quad << 3);
        bW = &Bs[0][wave << 9];
    }

    float4 la0 = make_float4(0.f, 0.f, 0.f, 0.f);
    float4 la1 = make_float4(0.f, 0.f, 0.f, 0.f);

    auto loadA = [&](int kt) {
        if (aValid) {
            la0 = *(const float4*)(aP + kt * 32);
            la1 = *(const float4*)(aP + kt * 32 + 4);
        }
    };
    auto writeA = [&](int buf) {
        const bf16x8 v = cvt8(la0, la1);
        *(bf16x8*)(aW + buf * 4096) = v;
    };
    auto issueB = [&](int kt, int buf) {
        if constexpr (TN == 256) {
            gl_lds16(bP + kt * 32,                bW + buf * (NFB * 512));
            gl_lds16(bP + kt * 32 + 16 * (long)K, bW + buf * (NFB * 512) + 512);
        } else {
            gl_lds16(bP + kt * 32,                bW + buf * (NFB * 512));
        }
    };

    issueB(0, 0);
    loadA(0);
    writeA(0);
    __syncthreads();

    for (int kt = 0; kt < nk; kt++) {
        const int cur = kt & 1;
        if (kt + 1 < nk) {
            issueB(kt + 1, cur ^ 1);
            loadA(kt + 1);
        }

        bf16x8 af[AI], bfr[4];
        #pragma unroll
        for (int i = 0; i < AI; i++)
            af[i] = *(const bf16x8*)&As[cur][(fA + i) * 512 + (lane << 3)];
        #pragma unroll
        for (int j = 0; j < 4; j++)
            bfr[j] = *(const bf16x8*)&Bs[cur][(fB + j) * 512 + (lane << 3)];
        #pragma unroll
        for (int i = 0; i < AI; i++)
            #pragma unroll
            for (int j = 0; j < 4; j++)
                acc[i][j] = __builtin_amdgcn_mfma_f32_16x16x32_bf16(
                    bfr[j], af[i], acc[i][j], 0, 0, 0);

        if (kt + 1 < nk) {
            writeA(cur ^ 1);
            __syncthreads();
        }
    }

    float4 bj[4];
    #pragma unroll
    for (int j = 0; j < 4; j++)
        bj[j] = *(const float4*)&bias[n0 + wn + j * 16 + (quad << 2)];

    float* outp = (float*)Cout;
    float bscale = 1.0f;
    if (SPLITK > 1) {
        outp += (size_t)blockIdx.z * M * N;        // partial buffer z
        bscale = (blockIdx.z == 0) ? 1.0f : 0.0f;
    }

    #pragma unroll
    for (int i = 0; i < AI; i++) {
        const long gr = m0 + wm + i * 16 + l16;
        if (gr < M) {
            #pragma unroll
            for (int j = 0; j < 4; j++) {
                float4 v;
                v.x = acc[i][j][0] + bscale * bj[j].x;
                v.y = acc[i][j][1] + bscale * bj[j].y;
                v.z = acc[i][j][2] + bscale * bj[j].z;
                v.w = acc[i][j][3] + bscale * bj[j].w;
                if (RELU) {
                    v.x = fmaxf(v.x, 0.f); v.y = fmaxf(v.y, 0.f);
                    v.z = fmaxf(v.z, 0.f); v.w = fmaxf(v.w, 0.f);
                }
                const int gc = n0 + wn + j * 16 + (quad << 2);
                if (OUTBF) {
                    unsigned short o[4] = {f2bf(v.x), f2bf(v.y), f2bf(v.z), f2bf(v.w)};
                    *(uint2*)((unsigned short*)Cout + gr * N + gc) = *(uint2*)o;
                } else {
                    *(float4*)(outp + gr * N + gc) = v;
                }
            }
        }
    }
}

// ---------------------------------------------------------------------------
// MFMA self-attention. Grid (5 q-tiles, 128 b*h).
// ---------------------------------------------------------------------------
__global__ __launch_bounds__(256) void attn_kernel(
    const float* __restrict__ qkv, float* __restrict__ sa)
{
    __shared__ union {
        struct {
            unsigned short Ks[304][40];
            unsigned short Qs[64][40];
        } s;
        unsigned short Ps[4][16][328];
    } u;
    __shared__ unsigned short Vt[32][328];

    const int bh = blockIdx.y;
    const int b  = bh >> 3, h = bh & 7;
    const int q0 = blockIdx.x * 64;
    const int t  = threadIdx.x;

    for (int idx = t; idx < 304 * 8; idx += 256) {
        const int r = idx >> 3, c4 = (idx & 7) << 2;
        if (r < NQ) {
            const float4 kv = *(const float4*)(qkv + ((long)(b * NQ + r)) * 768 + 256 + h * 32 + c4);
            u.s.Ks[r][c4 + 0] = f2bf(kv.x); u.s.Ks[r][c4 + 1] = f2bf(kv.y);
            u.s.Ks[r][c4 + 2] = f2bf(kv.z); u.s.Ks[r][c4 + 3] = f2bf(kv.w);
        } else {
            u.s.Ks[r][c4 + 0] = 0; u.s.Ks[r][c4 + 1] = 0;
            u.s.Ks[r][c4 + 2] = 0; u.s.Ks[r][c4 + 3] = 0;
        }
    }
    for (int idx = t; idx < NQ * 8; idx += 256) {
        const int key = idx >> 3, dq = (idx & 7) << 2;
        const float4 vv = *(const float4*)(qkv + ((long)(b * NQ + key)) * 768 + 512 + h * 32 + dq);
        Vt[dq + 0][key] = f2bf(vv.x); Vt[dq + 1][key] = f2bf(vv.y);
        Vt[dq + 2][key] = f2bf(vv.z); Vt[dq + 3][key] = f2bf(vv.w);
    }
    for (int idx = t; idx < 32 * 20; idx += 256)
        Vt[idx / 20][300 + idx % 20] = 0;
    for (int idx = t; idx < 64 * 8; idx += 256) {
        const int r = idx >> 3, c4 = (idx & 7) << 2;
        const int q = q0 + r;
        if (q < NQ) {
            const float4 qv = *(const float4*)(qkv + ((long)(b * NQ + q)) * 768 + h * 32 + c4);
            u.s.Qs[r][c4 + 0] = f2bf(qv.x); u.s.Qs[r][c4 + 1] = f2bf(qv.y);
            u.s.Qs[r][c4 + 2] = f2bf(qv.z); u.s.Qs[r][c4 + 3] = f2bf(qv.w);
        } else {
            u.s.Qs[r][c4 + 0] = 0; u.s.Qs[r][c4 + 1] = 0;
            u.s.Qs[r][c4 + 2] = 0; u.s.Qs[r][c4 + 3] = 0;
        }
    }
    __syncthreads();

    const int wave = t >> 6, lane = t & 63;
    const int l16 = lane & 15, quad = lane >> 4;
    const float scale = 0.1767766952966369f;

    const bf16x8 aq = *(const bf16x8*)&u.s.Qs[wave * 16 + l16][quad * 8];
    f32x4 sacc[19];
    #pragma unroll
    for (int kt = 0; kt < 19; kt++) {
        const bf16x8 bk = *(const bf16x8*)&u.s.Ks[kt * 16 + l16][quad * 8];
        sacc[kt] = __builtin_amdgcn_mfma_f32_16x16x32_bf16(
            aq, bk, (f32x4){0.f, 0.f, 0.f, 0.f}, 0, 0, 0);
    }

    float inv[4];
    #pragma unroll
    for (int r = 0; r < 4; r++) {
        float m = -1e30f;
        #pragma unroll
        for (int kt = 0; kt < 19; kt++) {
            float s = sacc[kt][r] * scale;
            if (kt == 18 && l16 >= 12) s = -1e30f;
            sacc[kt][r] = s;
            m = fmaxf(m, s);
        }
        m = fmaxf(m, __shfl_xor(m, 1)); m = fmaxf(m, __shfl_xor(m, 2));
        m = fmaxf(m, __shfl_xor(m, 4)); m = fmaxf(m, __shfl_xor(m, 8));
        float sum = 0.f;
        #pragma unroll
        for (int kt = 0; kt < 19; kt++) {
            float p = __expf(sacc[kt][r] - m);
            sacc[kt][r] = p;
            sum += p;
        }
        sum += __shfl_xor(sum, 1); sum += __shfl_xor(sum, 2);
        sum += __shfl_xor(sum, 4); sum += __shfl_xor(sum, 8);
        inv[r] = 1.0f / sum;
    }

    __syncthreads();

    #pragma unroll
    for (int kt = 0; kt < 19; kt++)
        #pragma unroll
        for (int r = 0; r < 4; r++)
            u.Ps[wave][quad * 4 + r][kt * 16 + l16] = f2bf(sacc[kt][r] * inv[r]);
    #pragma unroll
    for (int r = 0; r < 4; r++)
        u.Ps[wave][quad * 4 + r][304 + l16] = 0;

    f32x4 o0 = {0.f, 0.f, 0.f, 0.f}, o1 = {0.f, 0.f, 0.f, 0.f};
    #pragma unroll
    for (int kt = 0; kt < 10; kt++) {
        const bf16x8 ap  = *(const bf16x8*)&u.Ps[wave][l16][kt * 32 + quad * 8];
        const bf16x8 bv0 = *(const bf16x8*)&Vt[l16][kt * 32 + quad * 8];
        const bf16x8 bv1 = *(const bf16x8*)&Vt[16 + l16][kt * 32 + quad * 8];
        o0 = __builtin_amdgcn_mfma_f32_16x16x32_bf16(ap, bv0, o0, 0, 0, 0);
        o1 = __builtin_amdgcn_mfma_f32_16x16x32_bf16(ap, bv1, o1, 0, 0, 0);
    }

    #pragma unroll
    for (int r = 0; r < 4; r++) {
        const int q = q0 + wave * 16 + quad * 4 + r;
        if (q < NQ) {
            float* op = sa + ((long)(b * NQ + q)) * ND + h * 32;
            op[l16]      = o0[r];
            op[16 + l16] = o1[r];
        }
    }
}

// ---------------------------------------------------------------------------
// Residual + LayerNorm (NPART residual partials summed): one wave per row.
// ---------------------------------------------------------------------------
template <int NPART>
__global__ __launch_bounds__(256) void residual_ln(
    const float* __restrict__ a, const float* __restrict__ r,
    const float* __restrict__ gam, const float* __restrict__ bet,
    float* __restrict__ out, long pstride)
{
    const int row  = blockIdx.x * 4 + (threadIdx.x >> 6);
    const int lane = threadIdx.x & 63;
    const long base = (long)row * ND + lane * 4;
    float4 av = *(const float4*)(a + base);
    float4 rv = *(const float4*)(r + base);
    #pragma unroll
    for (int z = 1; z < NPART; z++) {
        float4 pv = *(const float4*)(r + z * pstride + base);
        rv.x += pv.x; rv.y += pv.y; rv.z += pv.z; rv.w += pv.w;
    }
    float x0 = av.x + rv.x, x1 = av.y + rv.y, x2 = av.z + rv.z, x3 = av.w + rv.w;
    float s  = x0 + x1 + x2 + x3;
    float s2 = x0 * x0 + x1 * x1 + x2 * x2 + x3 * x3;
    #pragma unroll
    for (int off = 32; off >= 1; off >>= 1) {
        s  += __shfl_xor(s, off);
        s2 += __shfl_xor(s2, off);
    }
    float mean = s * 0.00390625f;
    float var  = s2 * 0.00390625f - mean * mean;
    float rstd = rsqrtf(var + 1e-5f);
    float4 gv = *(const float4*)(gam + lane * 4);
    float4 bv = *(const float4*)(bet + lane * 4);
    float4 o;
    o.x = (x0 - mean) * rstd * gv.x + bv.x;
    o.y = (x1 - mean) * rstd * gv.y + bv.y;
    o.z = (x2 - mean) * rstd * gv.z + bv.z;
    o.w = (x3 - mean) * rstd * gv.w + bv.w;
    *(float4*)(out + base) = o;
}

// ---------------------------------------------------------------------------
// meta from head-GEMM result res[4800][128].
// ---------------------------------------------------------------------------
__global__ __launch_bounds__(256) void meta_kernel(
    const float* __restrict__ res, float* __restrict__ meta)
{
    const int t   = threadIdx.x;
    const int row = blockIdx.x * 8 + (t >> 5);
    const int s   = t & 31;
    const int h   = s >> 2;
    const float* rp = res + (long)row * 128;
    const float rx = 1.f / (1.f + __expf(-rp[0]));
    const float ry = 1.f / (1.f + __expf(-rp[1]));
    const float offx = rp[2 + 2 * s], offy = rp[3 + 2 * s];
    const float a0 = rp[66 + h * 4 + 0], a1 = rp[66 + h * 4 + 1];
    const float a2 = rp[66 + h * 4 + 2], a3 = rp[66 + h * 4 + 3];
    const float mx = fmaxf(fmaxf(a0, a1), fmaxf(a2, a3));
    const float den = __expf(a0 - mx) + __expf(a1 - mx) +
                      __expf(a2 - mx) + __expf(a3 - mx);
    const float awt = __expf(rp[66 + s] - mx) / den;

    const float lx = fminf(fmaxf(rx + offx, 0.f), 1.f) * (NWG - 1);
    const float ly = fminf(fmaxf(ry + offy, 0.f), 1.f) * (NWG - 1);
    const float fx = floorf(lx), fy = floorf(ly);
    int x0 = (int)fx; x0 = min(max(x0, 0), NWG - 1);
    int y0 = (int)fy; y0 = min(max(y0, 0), NWG - 1);
    const int x1 = min(x0 + 1, NWG - 1);
    const int y1 = min(y0 + 1, NWG - 1);
    const float wx1 = lx - fx, wx0 = 1.f - wx1;
    const float wy1 = ly - fy, wy0 = 1.f - wy1;
    float4 m0, m1;
    m0.x = __int_as_float(y0 * NWG + x0);
    m0.y = __int_as_float(y0 * NWG + x1);
    m0.z = __int_as_float(y1 * NWG + x0);
    m0.w = __int_as_float(y1 * NWG + x1);
    m1.x = awt * wx0 * wy0;
    m1.y = awt * wx1 * wy0;
    m1.z = awt * wx0 * wy1;
    m1.w = awt * wx1 * wy1;
    float* mp = meta + (long)row * 256 + s * 8;
    *(float4*)mp       = m0;
    *(float4*)(mp + 4) = m1;
}

// ---------------------------------------------------------------------------
// Deformable gather: block per (b,q); thread (h = t>>5, d = t&31).
// ---------------------------------------------------------------------------
__global__ __launch_bounds__(256) void deform_gather(
    const float* __restrict__ meta, const unsigned short* __restrict__ vals,
    float* __restrict__ ca)
{
    const int row = blockIdx.x;
    const int b = row / NQ;
    __shared__ float ms[256];
    const int t = threadIdx.x;
    ms[t] = meta[(long)row * 256 + t];
    __syncthreads();
    const int h = t >> 5, d = t & 31;
    const unsigned short* vb = vals + (long)b * NHW * ND + h * 32 + d;
    float acc = 0.f;
    #pragma unroll
    for (int p = 0; p < NP; p++) {
        const float* mp = ms + h * 32 + p * 8;
        const int i00 = __float_as_int(mp[0]);
        const int i01 = __float_as_int(mp[1]);
        const int i10 = __float_as_int(mp[2]);
        const int i11 = __float_as_int(mp[3]);
        acc += mp[4] * bf2f(vb[(long)i00 * ND]);
        acc += mp[5] * bf2f(vb[(long)i01 * ND]);
        acc += mp[6] * bf2f(vb[(long)i10 * ND]);
        acc += mp[7] * bf2f(vb[(long)i11 * ND]);
    }
    ca[(long)row * ND + t] = acc;
}

// ---------------------------------------------------------------------------
extern "C" void kernel_launch(void* const* d_in, const int* in_sizes, int n_in,
                              void* d_out, int out_size, void* d_ws, size_t ws_size,
                              hipStream_t stream)
{
    (void)in_sizes; (void)n_in; (void)out_size; (void)ws_size;
    const float* tgt   = (const float*)d_in[0];
    const float* mem   = (const float*)d_in[1];
    const float* inpw  = (const float*)d_in[2];
    const float* inpb  = (const float*)d_in[3];
    const float* outw  = (const float*)d_in[4];
    const float* outb  = (const float*)d_in[5];
    const float* n1g   = (const float*)d_in[6];
    const float* n1b   = (const float*)d_in[7];
    const float* refw  = (const float*)d_in[8];
    const float* refb  = (const float*)d_in[9];
    const float* offw  = (const float*)d_in[10];
    const float* offb  = (const float*)d_in[11];
    const float* attww = (const float*)d_in[12];
    const float* attwb = (const float*)d_in[13];
    const float* vpw   = (const float*)d_in[14];
    const float* vpb   = (const float*)d_in[15];
    const float* opw   = (const float*)d_in[16];
    const float* opb   = (const float*)d_in[17];
    const float* n2g   = (const float*)d_in[18];
    const float* n2b   = (const float*)d_in[19];
    const float* l1w   = (const float*)d_in[20];
    const float* l1b   = (const float*)d_in[21];
    const float* l2w   = (const float*)d_in[22];
    const float* l2b   = (const float*)d_in[23];
    const float* n3g   = (const float*)d_in[24];
    const float* n3b   = (const float*)d_in[25];
    float* out = (float*)d_out;

    char* p = (char*)d_ws;
    auto alloc = [&](size_t bytes) {
        char* r = p; p += (bytes + 255) & ~(size_t)255; return (void*)r;
    };
    unsigned short* wtIn   = (unsigned short*)alloc(768 * 256 * 2);
    unsigned short* wtOut  = (unsigned short*)alloc(256 * 256 * 2);
    unsigned short* wtVp   = (unsigned short*)alloc(256 * 256 * 2);
    unsigned short* wtOp   = (unsigned short*)alloc(256 * 256 * 2);
    unsigned short* wtL1   = (unsigned short*)alloc(2048 * 256 * 2);
    unsigned short* wtL2   = (unsigned short*)alloc(256 * 2048 * 2);
    unsigned short* wtHead = (unsigned short*)alloc(128 * 256 * 2);
    float*          headb  = (float*)alloc(128 * 4);
    float* qkv  = (float*)alloc((size_t)NROW * 768 * 4);
    float* sa   = (float*)alloc((size_t)NROW * ND * 4);
    float* x1   = (float*)alloc((size_t)NROW * ND * 4);
    float* x2   = (float*)alloc((size_t)NROW * ND * 4);
    float* tmp  = (float*)alloc((size_t)NROW * ND * 4 * 4);   // 4 split-K partials
    float* ca   = (float*)alloc((size_t)NROW * ND * 4);
    float* meta = (float*)alloc((size_t)NROW * 256 * 4);
    void* uni = alloc((size_t)NB * NHW * ND * 2);   // vals bf16 / h1 fp32 alias
    unsigned short* vals = (unsigned short*)uni;
    float* h1 = (float*)uni;
    float* res = qkv;   // head-GEMM result; qkv dead by then

    transpose_cast<<<352, 256, 0, stream>>>(
        inpw, outw, vpw, opw, l1w, l2w,
        wtIn, wtOut, wtVp, wtOp, wtL1, wtL2);
    prep_head<<<129, 256, 0, stream>>>(refw, refb, offw, offb, attww, attwb,
                                       wtHead, headb);

    gemm_bt<0, 0, 1, 256><<<dim3(3, 38), 512, 0, stream>>>(tgt, wtIn, inpb, qkv,
                                                           NROW, 768, 256);
    gemm_vproj_bs<<<250, 512, 0, stream>>>(mem, wtVp, vpb, vals);
    attn_kernel<<<dim3(5, 128), 256, 0, stream>>>(qkv, sa);
    gemm_bt<0, 0, 1, 256><<<dim3(1, 38), 512, 0, stream>>>(sa, wtOut, outb, tmp,
                                                           NROW, 256, 256);
    residual_ln<1><<<1200, 256, 0, stream>>>(tgt, tmp, n1g, n1b, x1, 0);
    gemm_bt<0, 0, 1, 128><<<dim3(1, 38), 512, 0, stream>>>(x1, wtHead, headb, res,
                                                           NROW, 128, 256);
    meta_kernel<<<600, 256, 0, stream>>>(res, meta);
    deform_gather<<<4800, 256, 0, stream>>>(meta, vals, ca);
    gemm_bt<0, 0, 1, 256><<<dim3(1, 38), 512, 0, stream>>>(ca, wtOp, opb, tmp,
                                                           NROW, 256, 256);
    residual_ln<1><<<1200, 256, 0, stream>>>(x1, tmp, n2g, n2b, x2, 0);
    gemm_bt<1, 0, 1, 256><<<dim3(8, 38), 512, 0, stream>>>(x2, wtL1, l1b, h1,
                                                           NROW, 2048, 256);
    gemm_bt<0, 0, 4, 256><<<dim3(1, 38, 4), 512, 0, stream>>>(h1, wtL2, l2b, tmp,
                                                              NROW, 256, 2048);
    residual_ln<4><<<1200, 256, 0, stream>>>(x2, tmp, n3g, n3b, out,
                                             (long)NROW * 256);
}

// Round 7
// 480.564 us; speedup vs baseline: 1.0833x; 1.0594x over previous
//
#include <hip/hip_runtime.h>

// Problem constants
#define NB   16
#define NQ   300
#define ND   256
#define NH   8
#define NP   4
#define NF   2048
#define NHW  10000
#define NWG  100
#define NROW 4800          // NB*NQ

typedef __attribute__((ext_vector_type(8))) short bf16x8;
typedef __attribute__((ext_vector_type(4))) float f32x4;

__device__ __forceinline__ unsigned short f2bf(float f) {
    unsigned u = __builtin_bit_cast(unsigned, f);
    u = (u + 0x7fffu + ((u >> 16) & 1u)) >> 16;   // RNE
    return (unsigned short)u;
}
__device__ __forceinline__ float bf2f(unsigned short h) {
    unsigned u = ((unsigned)h) << 16;
    return __builtin_bit_cast(float, u);
}

// 8 fp32 -> 8 bf16 (RNE) via packed cvt: 4 VALU instrs instead of ~32.
__device__ __forceinline__ bf16x8 cvt8(float4 lo, float4 hi) {
    unsigned r0, r1, r2, r3;
    asm("v_cvt_pk_bf16_f32 %0, %1, %2" : "=v"(r0) : "v"(lo.x), "v"(lo.y));
    asm("v_cvt_pk_bf16_f32 %0, %1, %2" : "=v"(r1) : "v"(lo.z), "v"(lo.w));
    asm("v_cvt_pk_bf16_f32 %0, %1, %2" : "=v"(r2) : "v"(hi.x), "v"(hi.y));
    asm("v_cvt_pk_bf16_f32 %0, %1, %2" : "=v"(r3) : "v"(hi.z), "v"(hi.w));
    uint4 u = {r0, r1, r2, r3};
    return __builtin_bit_cast(bf16x8, u);
}

// async global->LDS DMA, 16B per lane; LDS base wave-uniform, HW adds lane*16
__device__ __forceinline__ void gl_lds16(const unsigned short* g, unsigned short* l) {
    __builtin_amdgcn_global_load_lds(
        (__attribute__((address_space(1))) const void*)g,
        (__attribute__((address_space(3))) void*)l,
        16, 0, 0);
}
__device__ __forceinline__ void gl_lds16f(const float* g, float* l) {
    __builtin_amdgcn_global_load_lds(
        (__attribute__((address_space(1))) const void*)g,
        (__attribute__((address_space(3))) void*)l,
        16, 0, 0);
}

// ---------------------------------------------------------------------------
// Tiled transpose+cast: fp32 [K][N] -> bf16 [N][K] for the six GEMM weights.
// ---------------------------------------------------------------------------
__global__ __launch_bounds__(256) void transpose_cast(
    const float* __restrict__ w_in,  const float* __restrict__ w_out,
    const float* __restrict__ w_vp,  const float* __restrict__ w_op,
    const float* __restrict__ w_l1,  const float* __restrict__ w_l2,
    unsigned short* __restrict__ o_in, unsigned short* __restrict__ o_out,
    unsigned short* __restrict__ o_vp, unsigned short* __restrict__ o_op,
    unsigned short* __restrict__ o_l1, unsigned short* __restrict__ o_l2)
{
    __shared__ float ts[64][65];
    int b = blockIdx.x;
    const float* src; unsigned short* dst; int K, N, ncx;
    if      (b < 48)  { src = w_in;  dst = o_in;  K = 256;  N = 768;  ncx = 12; }
    else if (b < 64)  { src = w_out; dst = o_out; K = 256;  N = 256;  ncx = 4;  b -= 48; }
    else if (b < 80)  { src = w_vp;  dst = o_vp;  K = 256;  N = 256;  ncx = 4;  b -= 64; }
    else if (b < 96)  { src = w_op;  dst = o_op;  K = 256;  N = 256;  ncx = 4;  b -= 80; }
    else if (b < 224) { src = w_l1;  dst = o_l1;  K = 256;  N = 2048; ncx = 32; b -= 96; }
    else              { src = w_l2;  dst = o_l2;  K = 2048; N = 256;  ncx = 4;  b -= 224; }
    const int n0 = (b % ncx) * 64, k0 = (b / ncx) * 64;
    const int t = threadIdx.x;
    const int r = t >> 4, c = t & 15;
    #pragma unroll
    for (int j = 0; j < 4; j++) {
        float4 v = *(const float4*)(src + (long)(k0 + j * 16 + r) * N + n0 + c * 4);
        ts[j * 16 + r][c * 4 + 0] = v.x;
        ts[j * 16 + r][c * 4 + 1] = v.y;
        ts[j * 16 + r][c * 4 + 2] = v.z;
        ts[j * 16 + r][c * 4 + 3] = v.w;
    }
    __syncthreads();
    #pragma unroll
    for (int j = 0; j < 4; j++) {
        unsigned short o[4];
        #pragma unroll
        for (int i = 0; i < 4; i++)
            o[i] = f2bf(ts[c * 4 + i][j * 16 + r]);
        *(uint2*)(dst + (long)(n0 + j * 16 + r) * K + k0 + c * 4) = *(uint2*)o;
    }
}

// ---------------------------------------------------------------------------
// Head weights: concat ref/off/attw -> bf16 [128][256] + fp32 bias[128].
// ---------------------------------------------------------------------------
__global__ __launch_bounds__(256) void prep_head(
    const float* __restrict__ rw, const float* __restrict__ rb,
    const float* __restrict__ ow, const float* __restrict__ ob,
    const float* __restrict__ aw, const float* __restrict__ ab,
    unsigned short* __restrict__ o_hd, float* __restrict__ o_hb)
{
    int id = blockIdx.x * 256 + threadIdx.x;
    if (id < 32768) {
        int n = id >> 8, k = id & 255;
        float v;
        if (n < 2)       v = rw[k * 2 + n];
        else if (n < 66) v = ow[k * 64 + (n - 2)];
        else if (n < 98) v = aw[k * 32 + (n - 66)];
        else             v = 0.0f;
        o_hd[id] = f2bf(v);
        return;
    }
    id -= 32768;
    if (id < 128) {
        float v;
        if (id < 2)       v = rb[id];
        else if (id < 66) v = ob[id - 2];
        else if (id < 98) v = ab[id - 66];
        else              v = 0.0f;
        o_hb[id] = v;
    }
}

// ---------------------------------------------------------------------------
// B-STATIONARY vproj GEMM, DMA-pipelined:
//   C[160000,256](bf16) = A(fp32) * Bt[256,256]^T + bias.
// B (128KB bf16) resident in LDS, fragment-linear. A is staged through LDS
// as RAW FP32 via global_load_lds (hardware DMA -> zero VGPR pressure, can't
// be spilled/sunk — the r4-r6 failure mode). Double-buffered 16-row tiles
// (2 x 16KB): issue A(it+1) at top of iter, consume at it+1 -> full compute
// phase (~2k cy) covers HBM latency. Counted s_waitcnt vmcnt(2) + RAW
// s_barrier per iter (no vmcnt drain; in-order retirement means older
// gl_lds + C-stores complete first). LDS = 160KB exactly, 1 block/CU.
// 250 blocks x 640 rows; 8 waves (1m x 8n), per-wave 16 x 32 out (acc[2]).
// ---------------------------------------------------------------------------
__global__ __launch_bounds__(512, 2) void gemm_vproj_bs(
    const float* __restrict__ A, const unsigned short* __restrict__ Bt,
    const float* __restrict__ bias, unsigned short* __restrict__ Cout)
{
    // B frag(nf,kf) = 1KB lane-linear block at shorts [(nf*8+kf)*512]
    __shared__ __align__(16) unsigned short Bs[128 * 512];   // 128 KB
    // A frag kf = 2KB: half0 (floats 0-3 per lane) then half1 (floats 4-7)
    __shared__ __align__(16) float As[2][16 * 256];          // 2 x 16 KB

    const int t    = threadIdx.x;
    const int wave = t >> 6, lane = t & 63;
    const int l16  = lane & 15, quad = lane >> 4;
    const long m0  = (long)blockIdx.x * 640;

    // ---- stage all of B: wave stages n-frags 2w, 2w+1 (16 gl_lds) ----
    {
        const unsigned short* bp = Bt + (long)(wave * 32 + l16) * 256 + (quad << 3);
        unsigned short* bw = &Bs[wave << 13];
        #pragma unroll
        for (int kf = 0; kf < 8; kf++) {
            gl_lds16(bp + kf * 32,            bw + kf * 512);
            gl_lds16(bp + kf * 32 + 16 * 256, bw + 4096 + kf * 512);
        }
    }

    // A tile staging: wave stages fragment kf=wave of the 16-row tile.
    // global: lane(l16=row, quad) -> A[(m0+it*16+l16)*256 + wave*32 + quad*8]
    const float* aG = A + (m0 + l16) * 256 + wave * 32 + (quad << 3);
    auto issueA = [&](int it, int buf) {
        const float* g = aG + (long)it * 16 * 256;
        gl_lds16f(g,     &As[buf][wave * 512]);          // half0: floats 0-3
        gl_lds16f(g + 4, &As[buf][wave * 512 + 256]);    // half1: floats 4-7
    };

    issueA(0, 0);
    __syncthreads();   // drains vmcnt(0): B and A(0) resident

    float4 bj0 = *(const float4*)&bias[wave * 32 + (quad << 2)];
    float4 bj1 = *(const float4*)&bias[wave * 32 + 16 + (quad << 2)];

    // this wave's two B n-frag bases (kf stride = 512 shorts)
    const unsigned short* bF0 = &Bs[(wave << 13)] + (lane << 3);
    const unsigned short* bF1 = bF0 + 4096;

    for (int it = 0; it < 40; ++it) {
        const int cur = it & 1;
        if (it + 1 < 40) {
            issueA(it + 1, cur ^ 1);
            // wait all but the 2 newest (A(it+1)): A(it) + older C-stores done
            asm volatile("s_waitcnt vmcnt(2)" ::: "memory");
        } else {
            asm volatile("s_waitcnt vmcnt(0)" ::: "memory");
        }
        __builtin_amdgcn_sched_barrier(0);

        f32x4 acc0 = {0.f, 0.f, 0.f, 0.f}, acc1 = {0.f, 0.f, 0.f, 0.f};
        #pragma unroll
        for (int kf = 0; kf < 8; kf++) {
            const float4 alo = *(const float4*)&As[cur][kf * 512 + (lane << 2)];
            const float4 ahi = *(const float4*)&As[cur][kf * 512 + 256 + (lane << 2)];
            const bf16x8 af  = cvt8(alo, ahi);
            const bf16x8 bv0 = *(const bf16x8*)(bF0 + kf * 512);
            const bf16x8 bv1 = *(const bf16x8*)(bF1 + kf * 512);
            acc0 = __builtin_amdgcn_mfma_f32_16x16x32_bf16(bv0, af, acc0, 0, 0, 0);
            acc1 = __builtin_amdgcn_mfma_f32_16x16x32_bf16(bv1, af, acc1, 0, 0, 0);
        }

        const long gr = m0 + (long)it * 16 + l16;
        unsigned short* cp = Cout + gr * 256 + wave * 32 + (quad << 2);
        {
            unsigned short o[4] = {f2bf(acc0[0] + bj0.x), f2bf(acc0[1] + bj0.y),
                                   f2bf(acc0[2] + bj0.z), f2bf(acc0[3] + bj0.w)};
            *(uint2*)cp = *(uint2*)o;
        }
        {
            unsigned short o[4] = {f2bf(acc1[0] + bj1.x), f2bf(acc1[1] + bj1.y),
                                   f2bf(acc1[2] + bj1.z), f2bf(acc1[3] + bj1.w)};
            *(uint2*)(cp + 16) = *(uint2*)o;
        }

        // RAW barrier (no drain): separates reads(it) from issue(it+2)->buf[cur]
        __builtin_amdgcn_s_barrier();
    }
}

// ---------------------------------------------------------------------------
// bf16 MFMA GEMM: C[M,N] = A[M,K](fp32) * Bt[N,K](bf16)^T + bias.
// Tile 128 x TN (TN = 128 or 256), 512 threads = 8 waves.
// Fragment-linear LDS (conflict-free, measured 0), gl_lds B staging,
// reg-staged A (T14). SPLITK>1 writes partial fp32 sums to Cout + z*M*N.
// ---------------------------------------------------------------------------
template <int RELU, int OUTBF, int SPLITK, int TN>
__global__ __launch_bounds__(512, 4) void gemm_bt(
    const float* __restrict__ A, const unsigned short* __restrict__ Bt,
    const float* __restrict__ bias, void* __restrict__ Cout,
    int M, int N, int K)
{
    constexpr int NFB = TN / 16;          // B fragments per K-step (8 or 16)
    constexpr int WN  = TN / 64;          // waves along n (2 or 4)
    constexpr int AI  = WN;               // A-frags per wave (2 or 4)

    __shared__ __align__(16) unsigned short As[2][8 * 512];     // 8KB/buf
    __shared__ __align__(16) unsigned short Bs[2][NFB * 512];   // NFB KB/buf

    const int t    = threadIdx.x;
    const long m0  = (long)blockIdx.y * 128;
    const int  n0  = blockIdx.x * TN;
    const int  wave = t >> 6, lane = t & 63;
    const int  l16 = lane & 15, quad = lane >> 4;
    const int  wmi = wave / WN, wni = wave % WN;
    const int  wm  = wmi * (AI * 16);
    const int  wn  = wni * 64;
    const int  fA  = wmi * AI;
    const int  fB  = wni * 4;

    f32x4 acc[AI][4] = {};

    const int kChunk = K / SPLITK;
    const int kBeg   = (SPLITK > 1) ? blockIdx.z * kChunk : 0;
    const int nk     = kChunk / 32;

    const long aRow   = m0 + wave * 16 + l16;
    const bool aValid = (aRow < M);
    const float* aP   = A + aRow * (long)K + kBeg + (quad << 3);
    unsigned short* aW = &As[0][(wave << 9) + (lane << 3)];   // +buf*4096 shorts

    const unsigned short* bP;
    unsigned short* bW;
    if constexpr (TN == 256) {
        bP = Bt + (long)(n0 + wave * 32 + l16) * K + kBeg + (quad << 3);
        bW = &Bs[0][wave << 10];
    } else {
        bP = Bt + (long)(n0 + wave * 16 + l16) * K + kBeg + (quad << 3);
        bW = &Bs[0][wave << 9];
    }

    float4 la0 = make_float4(0.f, 0.f, 0.f, 0.f);
    float4 la1 = make_float4(0.f, 0.f, 0.f, 0.f);

    auto loadA = [&](int kt) {
        if (aValid) {
            la0 = *(const float4*)(aP + kt * 32);
            la1 = *(const float4*)(aP + kt * 32 + 4);
        }
    };
    auto writeA = [&](int buf) {
        const bf16x8 v = cvt8(la0, la1);
        *(bf16x8*)(aW + buf * 4096) = v;
    };
    auto issueB = [&](int kt, int buf) {
        if constexpr (TN == 256) {
            gl_lds16(bP + kt * 32,                bW + buf * (NFB * 512));
            gl_lds16(bP + kt * 32 + 16 * (long)K, bW + buf * (NFB * 512) + 512);
        } else {
            gl_lds16(bP + kt * 32,                bW + buf * (NFB * 512));
        }
    };

    issueB(0, 0);
    loadA(0);
    writeA(0);
    __syncthreads();

    for (int kt = 0; kt < nk; kt++) {
        const int cur = kt & 1;
        if (kt + 1 < nk) {
            issueB(kt + 1, cur ^ 1);
            loadA(kt + 1);
        }

        bf16x8 af[AI], bfr[4];
        #pragma unroll
        for (int i = 0; i < AI; i++)
            af[i] = *(const bf16x8*)&As[cur][(fA + i) * 512 + (lane << 3)];
        #pragma unroll
        for (int j = 0; j < 4; j++)
            bfr[j] = *(const bf16x8*)&Bs[cur][(fB + j) * 512 + (lane << 3)];
        #pragma unroll
        for (int i = 0; i < AI; i++)
            #pragma unroll
            for (int j = 0; j < 4; j++)
                acc[i][j] = __builtin_amdgcn_mfma_f32_16x16x32_bf16(
                    bfr[j], af[i], acc[i][j], 0, 0, 0);

        if (kt + 1 < nk) {
            writeA(cur ^ 1);
            __syncthreads();
        }
    }

    float4 bj[4];
    #pragma unroll
    for (int j = 0; j < 4; j++)
        bj[j] = *(const float4*)&bias[n0 + wn + j * 16 + (quad << 2)];

    float* outp = (float*)Cout;
    float bscale = 1.0f;
    if (SPLITK > 1) {
        outp += (size_t)blockIdx.z * M * N;        // partial buffer z
        bscale = (blockIdx.z == 0) ? 1.0f : 0.0f;
    }

    #pragma unroll
    for (int i = 0; i < AI; i++) {
        const long gr = m0 + wm + i * 16 + l16;
        if (gr < M) {
            #pragma unroll
            for (int j = 0; j < 4; j++) {
                float4 v;
                v.x = acc[i][j][0] + bscale * bj[j].x;
                v.y = acc[i][j][1] + bscale * bj[j].y;
                v.z = acc[i][j][2] + bscale * bj[j].z;
                v.w = acc[i][j][3] + bscale * bj[j].w;
                if (RELU) {
                    v.x = fmaxf(v.x, 0.f); v.y = fmaxf(v.y, 0.f);
                    v.z = fmaxf(v.z, 0.f); v.w = fmaxf(v.w, 0.f);
                }
                const int gc = n0 + wn + j * 16 + (quad << 2);
                if (OUTBF) {
                    unsigned short o[4] = {f2bf(v.x), f2bf(v.y), f2bf(v.z), f2bf(v.w)};
                    *(uint2*)((unsigned short*)Cout + gr * N + gc) = *(uint2*)o;
                } else {
                    *(float4*)(outp + gr * N + gc) = v;
                }
            }
        }
    }
}

// ---------------------------------------------------------------------------
// MFMA self-attention. Grid (5 q-tiles, 128 b*h).
// ---------------------------------------------------------------------------
__global__ __launch_bounds__(256) void attn_kernel(
    const float* __restrict__ qkv, float* __restrict__ sa)
{
    __shared__ union {
        struct {
            unsigned short Ks[304][40];
            unsigned short Qs[64][40];
        } s;
        unsigned short Ps[4][16][328];
    } u;
    __shared__ unsigned short Vt[32][328];

    const int bh = blockIdx.y;
    const int b  = bh >> 3, h = bh & 7;
    const int q0 = blockIdx.x * 64;
    const int t  = threadIdx.x;

    for (int idx = t; idx < 304 * 8; idx += 256) {
        const int r = idx >> 3, c4 = (idx & 7) << 2;
        if (r < NQ) {
            const float4 kv = *(const float4*)(qkv + ((long)(b * NQ + r)) * 768 + 256 + h * 32 + c4);
            u.s.Ks[r][c4 + 0] = f2bf(kv.x); u.s.Ks[r][c4 + 1] = f2bf(kv.y);
            u.s.Ks[r][c4 + 2] = f2bf(kv.z); u.s.Ks[r][c4 + 3] = f2bf(kv.w);
        } else {
            u.s.Ks[r][c4 + 0] = 0; u.s.Ks[r][c4 + 1] = 0;
            u.s.Ks[r][c4 + 2] = 0; u.s.Ks[r][c4 + 3] = 0;
        }
    }
    for (int idx = t; idx < NQ * 8; idx += 256) {
        const int key = idx >> 3, dq = (idx & 7) << 2;
        const float4 vv = *(const float4*)(qkv + ((long)(b * NQ + key)) * 768 + 512 + h * 32 + dq);
        Vt[dq + 0][key] = f2bf(vv.x); Vt[dq + 1][key] = f2bf(vv.y);
        Vt[dq + 2][key] = f2bf(vv.z); Vt[dq + 3][key] = f2bf(vv.w);
    }
    for (int idx = t; idx < 32 * 20; idx += 256)
        Vt[idx / 20][300 + idx % 20] = 0;
    for (int idx = t; idx < 64 * 8; idx += 256) {
        const int r = idx >> 3, c4 = (idx & 7) << 2;
        const int q = q0 + r;
        if (q < NQ) {
            const float4 qv = *(const float4*)(qkv + ((long)(b * NQ + q)) * 768 + h * 32 + c4);
            u.s.Qs[r][c4 + 0] = f2bf(qv.x); u.s.Qs[r][c4 + 1] = f2bf(qv.y);
            u.s.Qs[r][c4 + 2] = f2bf(qv.z); u.s.Qs[r][c4 + 3] = f2bf(qv.w);
        } else {
            u.s.Qs[r][c4 + 0] = 0; u.s.Qs[r][c4 + 1] = 0;
            u.s.Qs[r][c4 + 2] = 0; u.s.Qs[r][c4 + 3] = 0;
        }
    }
    __syncthreads();

    const int wave = t >> 6, lane = t & 63;
    const int l16 = lane & 15, quad = lane >> 4;
    const float scale = 0.1767766952966369f;

    const bf16x8 aq = *(const bf16x8*)&u.s.Qs[wave * 16 + l16][quad * 8];
    f32x4 sacc[19];
    #pragma unroll
    for (int kt = 0; kt < 19; kt++) {
        const bf16x8 bk = *(const bf16x8*)&u.s.Ks[kt * 16 + l16][quad * 8];
        sacc[kt] = __builtin_amdgcn_mfma_f32_16x16x32_bf16(
            aq, bk, (f32x4){0.f, 0.f, 0.f, 0.f}, 0, 0, 0);
    }

    float inv[4];
    #pragma unroll
    for (int r = 0; r < 4; r++) {
        float m = -1e30f;
        #pragma unroll
        for (int kt = 0; kt < 19; kt++) {
            float s = sacc[kt][r] * scale;
            if (kt == 18 && l16 >= 12) s = -1e30f;
            sacc[kt][r] = s;
            m = fmaxf(m, s);
        }
        m = fmaxf(m, __shfl_xor(m, 1)); m = fmaxf(m, __shfl_xor(m, 2));
        m = fmaxf(m, __shfl_xor(m, 4)); m = fmaxf(m, __shfl_xor(m, 8));
        float sum = 0.f;
        #pragma unroll
        for (int kt = 0; kt < 19; kt++) {
            float p = __expf(sacc[kt][r] - m);
            sacc[kt][r] = p;
            sum += p;
        }
        sum += __shfl_xor(sum, 1); sum += __shfl_xor(sum, 2);
        sum += __shfl_xor(sum, 4); sum += __shfl_xor(sum, 8);
        inv[r] = 1.0f / sum;
    }

    __syncthreads();

    #pragma unroll
    for (int kt = 0; kt < 19; kt++)
        #pragma unroll
        for (int r = 0; r < 4; r++)
            u.Ps[wave][quad * 4 + r][kt * 16 + l16] = f2bf(sacc[kt][r] * inv[r]);
    #pragma unroll
    for (int r = 0; r < 4; r++)
        u.Ps[wave][quad * 4 + r][304 + l16] = 0;

    f32x4 o0 = {0.f, 0.f, 0.f, 0.f}, o1 = {0.f, 0.f, 0.f, 0.f};
    #pragma unroll
    for (int kt = 0; kt < 10; kt++) {
        const bf16x8 ap  = *(const bf16x8*)&u.Ps[wave][l16][kt * 32 + quad * 8];
        const bf16x8 bv0 = *(const bf16x8*)&Vt[l16][kt * 32 + quad * 8];
        const bf16x8 bv1 = *(const bf16x8*)&Vt[16 + l16][kt * 32 + quad * 8];
        o0 = __builtin_amdgcn_mfma_f32_16x16x32_bf16(ap, bv0, o0, 0, 0, 0);
        o1 = __builtin_amdgcn_mfma_f32_16x16x32_bf16(ap, bv1, o1, 0, 0, 0);
    }

    #pragma unroll
    for (int r = 0; r < 4; r++) {
        const int q = q0 + wave * 16 + quad * 4 + r;
        if (q < NQ) {
            float* op = sa + ((long)(b * NQ + q)) * ND + h * 32;
            op[l16]      = o0[r];
            op[16 + l16] = o1[r];
        }
    }
}

// ---------------------------------------------------------------------------
// Residual + LayerNorm (NPART residual partials summed): one wave per row.
// ---------------------------------------------------------------------------
template <int NPART>
__global__ __launch_bounds__(256) void residual_ln(
    const float* __restrict__ a, const float* __restrict__ r,
    const float* __restrict__ gam, const float* __restrict__ bet,
    float* __restrict__ out, long pstride)
{
    const int row  = blockIdx.x * 4 + (threadIdx.x >> 6);
    const int lane = threadIdx.x & 63;
    const long base = (long)row * ND + lane * 4;
    float4 av = *(const float4*)(a + base);
    float4 rv = *(const float4*)(r + base);
    #pragma unroll
    for (int z = 1; z < NPART; z++) {
        float4 pv = *(const float4*)(r + z * pstride + base);
        rv.x += pv.x; rv.y += pv.y; rv.z += pv.z; rv.w += pv.w;
    }
    float x0 = av.x + rv.x, x1 = av.y + rv.y, x2 = av.z + rv.z, x3 = av.w + rv.w;
    float s  = x0 + x1 + x2 + x3;
    float s2 = x0 * x0 + x1 * x1 + x2 * x2 + x3 * x3;
    #pragma unroll
    for (int off = 32; off >= 1; off >>= 1) {
        s  += __shfl_xor(s, off);
        s2 += __shfl_xor(s2, off);
    }
    float mean = s * 0.00390625f;
    float var  = s2 * 0.00390625f - mean * mean;
    float rstd = rsqrtf(var + 1e-5f);
    float4 gv = *(const float4*)(gam + lane * 4);
    float4 bv = *(const float4*)(bet + lane * 4);
    float4 o;
    o.x = (x0 - mean) * rstd * gv.x + bv.x;
    o.y = (x1 - mean) * rstd * gv.y + bv.y;
    o.z = (x2 - mean) * rstd * gv.z + bv.z;
    o.w = (x3 - mean) * rstd * gv.w + bv.w;
    *(float4*)(out + base) = o;
}

// ---------------------------------------------------------------------------
// meta from head-GEMM result res[4800][128].
// ---------------------------------------------------------------------------
__global__ __launch_bounds__(256) void meta_kernel(
    const float* __restrict__ res, float* __restrict__ meta)
{
    const int t   = threadIdx.x;
    const int row = blockIdx.x * 8 + (t >> 5);
    const int s   = t & 31;
    const int h   = s >> 2;
    const float* rp = res + (long)row * 128;
    const float rx = 1.f / (1.f + __expf(-rp[0]));
    const float ry = 1.f / (1.f + __expf(-rp[1]));
    const float offx = rp[2 + 2 * s], offy = rp[3 + 2 * s];
    const float a0 = rp[66 + h * 4 + 0], a1 = rp[66 + h * 4 + 1];
    const float a2 = rp[66 + h * 4 + 2], a3 = rp[66 + h * 4 + 3];
    const float mx = fmaxf(fmaxf(a0, a1), fmaxf(a2, a3));
    const float den = __expf(a0 - mx) + __expf(a1 - mx) +
                      __expf(a2 - mx) + __expf(a3 - mx);
    const float awt = __expf(rp[66 + s] - mx) / den;

    const float lx = fminf(fmaxf(rx + offx, 0.f), 1.f) * (NWG - 1);
    const float ly = fminf(fmaxf(ry + offy, 0.f), 1.f) * (NWG - 1);
    const float fx = floorf(lx), fy = floorf(ly);
    int x0 = (int)fx; x0 = min(max(x0, 0), NWG - 1);
    int y0 = (int)fy; y0 = min(max(y0, 0), NWG - 1);
    const int x1 = min(x0 + 1, NWG - 1);
    const int y1 = min(y0 + 1, NWG - 1);
    const float wx1 = lx - fx, wx0 = 1.f - wx1;
    const float wy1 = ly - fy, wy0 = 1.f - wy1;
    float4 m0, m1;
    m0.x = __int_as_float(y0 * NWG + x0);
    m0.y = __int_as_float(y0 * NWG + x1);
    m0.z = __int_as_float(y1 * NWG + x0);
    m0.w = __int_as_float(y1 * NWG + x1);
    m1.x = awt * wx0 * wy0;
    m1.y = awt * wx1 * wy0;
    m1.z = awt * wx0 * wy1;
    m1.w = awt * wx1 * wy1;
    float* mp = meta + (long)row * 256 + s * 8;
    *(float4*)mp       = m0;
    *(float4*)(mp + 4) = m1;
}

// ---------------------------------------------------------------------------
// Deformable gather: block per (b,q); thread (h = t>>5, d = t&31).
// ---------------------------------------------------------------------------
__global__ __launch_bounds__(256) void deform_gather(
    const float* __restrict__ meta, const unsigned short* __restrict__ vals,
    float* __restrict__ ca)
{
    const int row = blockIdx.x;
    const int b = row / NQ;
    __shared__ float ms[256];
    const int t = threadIdx.x;
    ms[t] = meta[(long)row * 256 + t];
    __syncthreads();
    const int h = t >> 5, d = t & 31;
    const unsigned short* vb = vals + (long)b * NHW * ND + h * 32 + d;
    float acc = 0.f;
    #pragma unroll
    for (int p = 0; p < NP; p++) {
        const float* mp = ms + h * 32 + p * 8;
        const int i00 = __float_as_int(mp[0]);
        const int i01 = __float_as_int(mp[1]);
        const int i10 = __float_as_int(mp[2]);
        const int i11 = __float_as_int(mp[3]);
        acc += mp[4] * bf2f(vb[(long)i00 * ND]);
        acc += mp[5] * bf2f(vb[(long)i01 * ND]);
        acc += mp[6] * bf2f(vb[(long)i10 * ND]);
        acc += mp[7] * bf2f(vb[(long)i11 * ND]);
    }
    ca[(long)row * ND + t] = acc;
}

// ---------------------------------------------------------------------------
extern "C" void kernel_launch(void* const* d_in, const int* in_sizes, int n_in,
                              void* d_out, int out_size, void* d_ws, size_t ws_size,
                              hipStream_t stream)
{
    (void)in_sizes; (void)n_in; (void)out_size; (void)ws_size;
    const float* tgt   = (const float*)d_in[0];
    const float* mem   = (const float*)d_in[1];
    const float* inpw  = (const float*)d_in[2];
    const float* inpb  = (const float*)d_in[3];
    const float* outw  = (const float*)d_in[4];
    const float* outb  = (const float*)d_in[5];
    const float* n1g   = (const float*)d_in[6];
    const float* n1b   = (const float*)d_in[7];
    const float* refw  = (const float*)d_in[8];
    const float* refb  = (const float*)d_in[9];
    const float* offw  = (const float*)d_in[10];
    const float* offb  = (const float*)d_in[11];
    const float* attww = (const float*)d_in[12];
    const float* attwb = (const float*)d_in[13];
    const float* vpw   = (const float*)d_in[14];
    const float* vpb   = (const float*)d_in[15];
    const float* opw   = (const float*)d_in[16];
    const float* opb   = (const float*)d_in[17];
    const float* n2g   = (const float*)d_in[18];
    const float* n2b   = (const float*)d_in[19];
    const float* l1w   = (const float*)d_in[20];
    const float* l1b   = (const float*)d_in[21];
    const float* l2w   = (const float*)d_in[22];
    const float* l2b   = (const float*)d_in[23];
    const float* n3g   = (const float*)d_in[24];
    const float* n3b   = (const float*)d_in[25];
    float* out = (float*)d_out;

    char* p = (char*)d_ws;
    auto alloc = [&](size_t bytes) {
        char* r = p; p += (bytes + 255) & ~(size_t)255; return (void*)r;
    };
    unsigned short* wtIn   = (unsigned short*)alloc(768 * 256 * 2);
    unsigned short* wtOut  = (unsigned short*)alloc(256 * 256 * 2);
    unsigned short* wtVp   = (unsigned short*)alloc(256 * 256 * 2);
    unsigned short* wtOp   = (unsigned short*)alloc(256 * 256 * 2);
    unsigned short* wtL1   = (unsigned short*)alloc(2048 * 256 * 2);
    unsigned short* wtL2   = (unsigned short*)alloc(256 * 2048 * 2);
    unsigned short* wtHead = (unsigned short*)alloc(128 * 256 * 2);
    float*          headb  = (float*)alloc(128 * 4);
    float* qkv  = (float*)alloc((size_t)NROW * 768 * 4);
    float* sa   = (float*)alloc((size_t)NROW * ND * 4);
    float* x1   = (float*)alloc((size_t)NROW * ND * 4);
    float* x2   = (float*)alloc((size_t)NROW * ND * 4);
    float* tmp  = (float*)alloc((size_t)NROW * ND * 4 * 4);   // 4 split-K partials
    float* ca   = (float*)alloc((size_t)NROW * ND * 4);
    float* meta = (float*)alloc((size_t)NROW * 256 * 4);
    void* uni = alloc((size_t)NB * NHW * ND * 2);   // vals bf16 / h1 fp32 alias
    unsigned short* vals = (unsigned short*)uni;
    float* h1 = (float*)uni;
    float* res = qkv;   // head-GEMM result; qkv dead by then

    transpose_cast<<<352, 256, 0, stream>>>(
        inpw, outw, vpw, opw, l1w, l2w,
        wtIn, wtOut, wtVp, wtOp, wtL1, wtL2);
    prep_head<<<129, 256, 0, stream>>>(refw, refb, offw, offb, attww, attwb,
                                       wtHead, headb);

    gemm_bt<0, 0, 1, 256><<<dim3(3, 38), 512, 0, stream>>>(tgt, wtIn, inpb, qkv,
                                                           NROW, 768, 256);
    gemm_vproj_bs<<<250, 512, 0, stream>>>(mem, wtVp, vpb, vals);
    attn_kernel<<<dim3(5, 128), 256, 0, stream>>>(qkv, sa);
    gemm_bt<0, 0, 2, 256><<<dim3(1, 38, 2), 512, 0, stream>>>(sa, wtOut, outb, tmp,
                                                              NROW, 256, 256);
    residual_ln<2><<<1200, 256, 0, stream>>>(tgt, tmp, n1g, n1b, x1,
                                             (long)NROW * 256);
    gemm_bt<0, 0, 1, 128><<<dim3(1, 38), 512, 0, stream>>>(x1, wtHead, headb, res,
                                                           NROW, 128, 256);
    meta_kernel<<<600, 256, 0, stream>>>(res, meta);
    deform_gather<<<4800, 256, 0, stream>>>(meta, vals, ca);
    gemm_bt<0, 0, 2, 256><<<dim3(1, 38, 2), 512, 0, stream>>>(ca, wtOp, opb, tmp,
                                                              NROW, 256, 256);
    residual_ln<2><<<1200, 256, 0, stream>>>(x1, tmp, n2g, n2b, x2,
                                             (long)NROW * 256);
    gemm_bt<1, 0, 1, 256><<<dim3(8, 38), 512, 0, stream>>>(x2, wtL1, l1b, h1,
                                                           NROW, 2048, 256);
    gemm_bt<0, 0, 4, 256><<<dim3(1, 38, 4), 512, 0, stream>>>(h1, wtL2, l2b, tmp,
                                                              NROW, 256, 2048);
    residual_ln<4><<<1200, 256, 0, stream>>>(x2, tmp, n3g, n3b, out,
                                             (long)NROW * 256);
}

// Round 8
// 470.124 us; speedup vs baseline: 1.1073x; 1.0222x over previous
//
#include <hip/hip_runtime.h>

// Problem constants
#define NB   16
#define NQ   300
#define ND   256
#define NH   8
#define NP   4
#define NF   2048
#define NHW  10000
#define NWG  100
#define NROW 4800          // NB*NQ

typedef __attribute__((ext_vector_type(8))) short bf16x8;
typedef __attribute__((ext_vector_type(4))) float f32x4;

__device__ __forceinline__ unsigned short f2bf(float f) {
    unsigned u = __builtin_bit_cast(unsigned, f);
    u = (u + 0x7fffu + ((u >> 16) & 1u)) >> 16;   // RNE
    return (unsigned short)u;
}
__device__ __forceinline__ float bf2f(unsigned short h) {
    unsigned u = ((unsigned)h) << 16;
    return __builtin_bit_cast(float, u);
}

// 8 fp32 -> 8 bf16 (RNE) via packed cvt: 4 VALU instrs instead of ~32.
__device__ __forceinline__ bf16x8 cvt8(float4 lo, float4 hi) {
    unsigned r0, r1, r2, r3;
    asm("v_cvt_pk_bf16_f32 %0, %1, %2" : "=v"(r0) : "v"(lo.x), "v"(lo.y));
    asm("v_cvt_pk_bf16_f32 %0, %1, %2" : "=v"(r1) : "v"(lo.z), "v"(lo.w));
    asm("v_cvt_pk_bf16_f32 %0, %1, %2" : "=v"(r2) : "v"(hi.x), "v"(hi.y));
    asm("v_cvt_pk_bf16_f32 %0, %1, %2" : "=v"(r3) : "v"(hi.z), "v"(hi.w));
    uint4 u = {r0, r1, r2, r3};
    return __builtin_bit_cast(bf16x8, u);
}

// async global->LDS DMA, 16B per lane; LDS base wave-uniform, HW adds lane*16
__device__ __forceinline__ void gl_lds16(const unsigned short* g, unsigned short* l) {
    __builtin_amdgcn_global_load_lds(
        (__attribute__((address_space(1))) const void*)g,
        (__attribute__((address_space(3))) void*)l,
        16, 0, 0);
}
__device__ __forceinline__ void gl_lds16f(const float* g, float* l) {
    __builtin_amdgcn_global_load_lds(
        (__attribute__((address_space(1))) const void*)g,
        (__attribute__((address_space(3))) void*)l,
        16, 0, 0);
}

// ---------------------------------------------------------------------------
// Tiled transpose+cast: fp32 [K][N] -> bf16 [N][K] for the six GEMM weights.
// ---------------------------------------------------------------------------
__global__ __launch_bounds__(256) void transpose_cast(
    const float* __restrict__ w_in,  const float* __restrict__ w_out,
    const float* __restrict__ w_vp,  const float* __restrict__ w_op,
    const float* __restrict__ w_l1,  const float* __restrict__ w_l2,
    unsigned short* __restrict__ o_in, unsigned short* __restrict__ o_out,
    unsigned short* __restrict__ o_vp, unsigned short* __restrict__ o_op,
    unsigned short* __restrict__ o_l1, unsigned short* __restrict__ o_l2)
{
    __shared__ float ts[64][65];
    int b = blockIdx.x;
    const float* src; unsigned short* dst; int K, N, ncx;
    if      (b < 48)  { src = w_in;  dst = o_in;  K = 256;  N = 768;  ncx = 12; }
    else if (b < 64)  { src = w_out; dst = o_out; K = 256;  N = 256;  ncx = 4;  b -= 48; }
    else if (b < 80)  { src = w_vp;  dst = o_vp;  K = 256;  N = 256;  ncx = 4;  b -= 64; }
    else if (b < 96)  { src = w_op;  dst = o_op;  K = 256;  N = 256;  ncx = 4;  b -= 80; }
    else if (b < 224) { src = w_l1;  dst = o_l1;  K = 256;  N = 2048; ncx = 32; b -= 96; }
    else              { src = w_l2;  dst = o_l2;  K = 2048; N = 256;  ncx = 4;  b -= 224; }
    const int n0 = (b % ncx) * 64, k0 = (b / ncx) * 64;
    const int t = threadIdx.x;
    const int r = t >> 4, c = t & 15;
    #pragma unroll
    for (int j = 0; j < 4; j++) {
        float4 v = *(const float4*)(src + (long)(k0 + j * 16 + r) * N + n0 + c * 4);
        ts[j * 16 + r][c * 4 + 0] = v.x;
        ts[j * 16 + r][c * 4 + 1] = v.y;
        ts[j * 16 + r][c * 4 + 2] = v.z;
        ts[j * 16 + r][c * 4 + 3] = v.w;
    }
    __syncthreads();
    #pragma unroll
    for (int j = 0; j < 4; j++) {
        unsigned short o[4];
        #pragma unroll
        for (int i = 0; i < 4; i++)
            o[i] = f2bf(ts[c * 4 + i][j * 16 + r]);
        *(uint2*)(dst + (long)(n0 + j * 16 + r) * K + k0 + c * 4) = *(uint2*)o;
    }
}

// ---------------------------------------------------------------------------
// Head weights: concat ref/off/attw -> bf16 [128][256] + fp32 bias[128].
// ---------------------------------------------------------------------------
__global__ __launch_bounds__(256) void prep_head(
    const float* __restrict__ rw, const float* __restrict__ rb,
    const float* __restrict__ ow, const float* __restrict__ ob,
    const float* __restrict__ aw, const float* __restrict__ ab,
    unsigned short* __restrict__ o_hd, float* __restrict__ o_hb)
{
    int id = blockIdx.x * 256 + threadIdx.x;
    if (id < 32768) {
        int n = id >> 8, k = id & 255;
        float v;
        if (n < 2)       v = rw[k * 2 + n];
        else if (n < 66) v = ow[k * 64 + (n - 2)];
        else if (n < 98) v = aw[k * 32 + (n - 66)];
        else             v = 0.0f;
        o_hd[id] = f2bf(v);
        return;
    }
    id -= 32768;
    if (id < 128) {
        float v;
        if (id < 2)       v = rb[id];
        else if (id < 66) v = ob[id - 2];
        else if (id < 98) v = ab[id - 66];
        else              v = 0.0f;
        o_hb[id] = v;
    }
}

// ---------------------------------------------------------------------------
// B-STATIONARY vproj GEMM, DMA-pipelined (r7 verified win — unchanged):
//   C[160000,256](bf16) = A(fp32) * Bt[256,256]^T + bias.
// B (128KB bf16) resident in LDS; A staged through LDS as raw fp32 via
// global_load_lds (zero VGPR pressure). Double-buffered 16-row tiles,
// counted s_waitcnt vmcnt(2) + RAW s_barrier per iter. 160KB LDS, 1 blk/CU.
// ---------------------------------------------------------------------------
__global__ __launch_bounds__(512, 2) void gemm_vproj_bs(
    const float* __restrict__ A, const unsigned short* __restrict__ Bt,
    const float* __restrict__ bias, unsigned short* __restrict__ Cout)
{
    __shared__ __align__(16) unsigned short Bs[128 * 512];   // 128 KB
    __shared__ __align__(16) float As[2][16 * 256];          // 2 x 16 KB

    const int t    = threadIdx.x;
    const int wave = t >> 6, lane = t & 63;
    const int l16  = lane & 15, quad = lane >> 4;
    const long m0  = (long)blockIdx.x * 640;

    {
        const unsigned short* bp = Bt + (long)(wave * 32 + l16) * 256 + (quad << 3);
        unsigned short* bw = &Bs[wave << 13];
        #pragma unroll
        for (int kf = 0; kf < 8; kf++) {
            gl_lds16(bp + kf * 32,            bw + kf * 512);
            gl_lds16(bp + kf * 32 + 16 * 256, bw + 4096 + kf * 512);
        }
    }

    const float* aG = A + (m0 + l16) * 256 + wave * 32 + (quad << 3);
    auto issueA = [&](int it, int buf) {
        const float* g = aG + (long)it * 16 * 256;
        gl_lds16f(g,     &As[buf][wave * 512]);          // half0: floats 0-3
        gl_lds16f(g + 4, &As[buf][wave * 512 + 256]);    // half1: floats 4-7
    };

    issueA(0, 0);
    __syncthreads();   // drains vmcnt(0): B and A(0) resident

    float4 bj0 = *(const float4*)&bias[wave * 32 + (quad << 2)];
    float4 bj1 = *(const float4*)&bias[wave * 32 + 16 + (quad << 2)];

    const unsigned short* bF0 = &Bs[(wave << 13)] + (lane << 3);
    const unsigned short* bF1 = bF0 + 4096;

    for (int it = 0; it < 40; ++it) {
        const int cur = it & 1;
        if (it + 1 < 40) {
            issueA(it + 1, cur ^ 1);
            asm volatile("s_waitcnt vmcnt(2)" ::: "memory");
        } else {
            asm volatile("s_waitcnt vmcnt(0)" ::: "memory");
        }
        __builtin_amdgcn_sched_barrier(0);

        f32x4 acc0 = {0.f, 0.f, 0.f, 0.f}, acc1 = {0.f, 0.f, 0.f, 0.f};
        #pragma unroll
        for (int kf = 0; kf < 8; kf++) {
            const float4 alo = *(const float4*)&As[cur][kf * 512 + (lane << 2)];
            const float4 ahi = *(const float4*)&As[cur][kf * 512 + 256 + (lane << 2)];
            const bf16x8 af  = cvt8(alo, ahi);
            const bf16x8 bv0 = *(const bf16x8*)(bF0 + kf * 512);
            const bf16x8 bv1 = *(const bf16x8*)(bF1 + kf * 512);
            acc0 = __builtin_amdgcn_mfma_f32_16x16x32_bf16(bv0, af, acc0, 0, 0, 0);
            acc1 = __builtin_amdgcn_mfma_f32_16x16x32_bf16(bv1, af, acc1, 0, 0, 0);
        }

        const long gr = m0 + (long)it * 16 + l16;
        unsigned short* cp = Cout + gr * 256 + wave * 32 + (quad << 2);
        {
            unsigned short o[4] = {f2bf(acc0[0] + bj0.x), f2bf(acc0[1] + bj0.y),
                                   f2bf(acc0[2] + bj0.z), f2bf(acc0[3] + bj0.w)};
            *(uint2*)cp = *(uint2*)o;
        }
        {
            unsigned short o[4] = {f2bf(acc1[0] + bj1.x), f2bf(acc1[1] + bj1.y),
                                   f2bf(acc1[2] + bj1.z), f2bf(acc1[3] + bj1.w)};
            *(uint2*)(cp + 16) = *(uint2*)o;
        }

        __builtin_amdgcn_s_barrier();   // RAW barrier, no vmcnt drain
    }
}

// ---------------------------------------------------------------------------
// bf16 MFMA GEMM: C[M,N] = A[M,K](fp32) * Bt[N,K](bf16)^T + bias.
// Tile TM x TN (TM in {64,128}, TN in {128,256}); threads = TM*4 = 4 or 8
// waves; always 1 A-frag staged per wave, NFB/W B-frags per wave.
// TM=64 doubles the y-grid (M=4800 -> 75 blocks, no tail) to fix the
// 38-block grid starvation of the 128-row tile on this problem's GEMMs.
// Fragment-linear LDS (conflict-free, measured 0), gl_lds B staging,
// reg-staged A (T14). SPLITK>1 writes partial fp32 sums to Cout + z*M*N.
// ---------------------------------------------------------------------------
template <int RELU, int OUTBF, int SPLITK, int TM, int TN>
__global__ __launch_bounds__(TM * 4, 4) void gemm_bt(
    const float* __restrict__ A, const unsigned short* __restrict__ Bt,
    const float* __restrict__ bias, void* __restrict__ Cout,
    int M, int N, int K)
{
    constexpr int W   = TM / 16;          // waves (4 or 8)
    constexpr int NFB = TN / 16;          // B fragments per K-step
    constexpr int WN  = TN / 64;          // waves along n
    constexpr int WM  = W / WN;           // waves along m
    constexpr int AI  = (TM / 16) / WM;   // A-frags consumed per wave
    constexpr int BPW = NFB / W;          // B-frags staged per wave

    __shared__ __align__(16) unsigned short As[2][W * 512];
    __shared__ __align__(16) unsigned short Bs[2][NFB * 512];

    const int t    = threadIdx.x;
    const long m0  = (long)blockIdx.y * TM;
    const int  n0  = blockIdx.x * TN;
    const int  wave = t >> 6, lane = t & 63;
    const int  l16 = lane & 15, quad = lane >> 4;
    const int  wmi = wave / WN, wni = wave % WN;
    const int  wm  = wmi * (AI * 16);
    const int  wn  = wni * 64;
    const int  fA  = wmi * AI;
    const int  fB  = wni * 4;

    f32x4 acc[AI][4] = {};

    const int kChunk = K / SPLITK;
    const int kBeg   = (SPLITK > 1) ? blockIdx.z * kChunk : 0;
    const int nk     = kChunk / 32;

    const long aRow   = m0 + wave * 16 + l16;
    const bool aValid = (aRow < M);
    const float* aP   = A + aRow * (long)K + kBeg + (quad << 3);
    unsigned short* aW = &As[0][(wave << 9) + (lane << 3)];   // +buf*(W*512)

    const unsigned short* bP =
        Bt + (long)(n0 + wave * (16 * BPW) + l16) * K + kBeg + (quad << 3);
    unsigned short* bW = &Bs[0][wave * BPW * 512];            // +buf*(NFB*512)

    float4 la0 = make_float4(0.f, 0.f, 0.f, 0.f);
    float4 la1 = make_float4(0.f, 0.f, 0.f, 0.f);

    auto loadA = [&](int kt) {
        if (aValid) {
            la0 = *(const float4*)(aP + kt * 32);
            la1 = *(const float4*)(aP + kt * 32 + 4);
        }
    };
    auto writeA = [&](int buf) {
        const bf16x8 v = cvt8(la0, la1);
        *(bf16x8*)(aW + buf * (W * 512)) = v;
    };
    auto issueB = [&](int kt, int buf) {
        #pragma unroll
        for (int j = 0; j < BPW; j++)
            gl_lds16(bP + kt * 32 + (long)j * 16 * K,
                     bW + buf * (NFB * 512) + j * 512);
    };

    issueB(0, 0);
    loadA(0);
    writeA(0);
    __syncthreads();

    for (int kt = 0; kt < nk; kt++) {
        const int cur = kt & 1;
        if (kt + 1 < nk) {
            issueB(kt + 1, cur ^ 1);
            loadA(kt + 1);
        }

        bf16x8 af[AI], bfr[4];
        #pragma unroll
        for (int i = 0; i < AI; i++)
            af[i] = *(const bf16x8*)&As[cur][(fA + i) * 512 + (lane << 3)];
        #pragma unroll
        for (int j = 0; j < 4; j++)
            bfr[j] = *(const bf16x8*)&Bs[cur][(fB + j) * 512 + (lane << 3)];
        #pragma unroll
        for (int i = 0; i < AI; i++)
            #pragma unroll
            for (int j = 0; j < 4; j++)
                acc[i][j] = __builtin_amdgcn_mfma_f32_16x16x32_bf16(
                    bfr[j], af[i], acc[i][j], 0, 0, 0);

        if (kt + 1 < nk) {
            writeA(cur ^ 1);
            __syncthreads();
        }
    }

    float4 bj[4];
    #pragma unroll
    for (int j = 0; j < 4; j++)
        bj[j] = *(const float4*)&bias[n0 + wn + j * 16 + (quad << 2)];

    float* outp = (float*)Cout;
    float bscale = 1.0f;
    if (SPLITK > 1) {
        outp += (size_t)blockIdx.z * M * N;        // partial buffer z
        bscale = (blockIdx.z == 0) ? 1.0f : 0.0f;
    }

    #pragma unroll
    for (int i = 0; i < AI; i++) {
        const long gr = m0 + wm + i * 16 + l16;
        if (gr < M) {
            #pragma unroll
            for (int j = 0; j < 4; j++) {
                float4 v;
                v.x = acc[i][j][0] + bscale * bj[j].x;
                v.y = acc[i][j][1] + bscale * bj[j].y;
                v.z = acc[i][j][2] + bscale * bj[j].z;
                v.w = acc[i][j][3] + bscale * bj[j].w;
                if (RELU) {
                    v.x = fmaxf(v.x, 0.f); v.y = fmaxf(v.y, 0.f);
                    v.z = fmaxf(v.z, 0.f); v.w = fmaxf(v.w, 0.f);
                }
                const int gc = n0 + wn + j * 16 + (quad << 2);
                if (OUTBF) {
                    unsigned short o[4] = {f2bf(v.x), f2bf(v.y), f2bf(v.z), f2bf(v.w)};
                    *(uint2*)((unsigned short*)Cout + gr * N + gc) = *(uint2*)o;
                } else {
                    *(float4*)(outp + gr * N + gc) = v;
                }
            }
        }
    }
}

// ---------------------------------------------------------------------------
// MFMA self-attention. Grid (5 q-tiles, 128 b*h).
// ---------------------------------------------------------------------------
__global__ __launch_bounds__(256) void attn_kernel(
    const float* __restrict__ qkv, float* __restrict__ sa)
{
    __shared__ union {
        struct {
            unsigned short Ks[304][40];
            unsigned short Qs[64][40];
        } s;
        unsigned short Ps[4][16][328];
    } u;
    __shared__ unsigned short Vt[32][328];

    const int bh = blockIdx.y;
    const int b  = bh >> 3, h = bh & 7;
    const int q0 = blockIdx.x * 64;
    const int t  = threadIdx.x;

    for (int idx = t; idx < 304 * 8; idx += 256) {
        const int r = idx >> 3, c4 = (idx & 7) << 2;
        if (r < NQ) {
            const float4 kv = *(const float4*)(qkv + ((long)(b * NQ + r)) * 768 + 256 + h * 32 + c4);
            u.s.Ks[r][c4 + 0] = f2bf(kv.x); u.s.Ks[r][c4 + 1] = f2bf(kv.y);
            u.s.Ks[r][c4 + 2] = f2bf(kv.z); u.s.Ks[r][c4 + 3] = f2bf(kv.w);
        } else {
            u.s.Ks[r][c4 + 0] = 0; u.s.Ks[r][c4 + 1] = 0;
            u.s.Ks[r][c4 + 2] = 0; u.s.Ks[r][c4 + 3] = 0;
        }
    }
    for (int idx = t; idx < NQ * 8; idx += 256) {
        const int key = idx >> 3, dq = (idx & 7) << 2;
        const float4 vv = *(const float4*)(qkv + ((long)(b * NQ + key)) * 768 + 512 + h * 32 + dq);
        Vt[dq + 0][key] = f2bf(vv.x); Vt[dq + 1][key] = f2bf(vv.y);
        Vt[dq + 2][key] = f2bf(vv.z); Vt[dq + 3][key] = f2bf(vv.w);
    }
    for (int idx = t; idx < 32 * 20; idx += 256)
        Vt[idx / 20][300 + idx % 20] = 0;
    for (int idx = t; idx < 64 * 8; idx += 256) {
        const int r = idx >> 3, c4 = (idx & 7) << 2;
        const int q = q0 + r;
        if (q < NQ) {
            const float4 qv = *(const float4*)(qkv + ((long)(b * NQ + q)) * 768 + h * 32 + c4);
            u.s.Qs[r][c4 + 0] = f2bf(qv.x); u.s.Qs[r][c4 + 1] = f2bf(qv.y);
            u.s.Qs[r][c4 + 2] = f2bf(qv.z); u.s.Qs[r][c4 + 3] = f2bf(qv.w);
        } else {
            u.s.Qs[r][c4 + 0] = 0; u.s.Qs[r][c4 + 1] = 0;
            u.s.Qs[r][c4 + 2] = 0; u.s.Qs[r][c4 + 3] = 0;
        }
    }
    __syncthreads();

    const int wave = t >> 6, lane = t & 63;
    const int l16 = lane & 15, quad = lane >> 4;
    const float scale = 0.1767766952966369f;

    const bf16x8 aq = *(const bf16x8*)&u.s.Qs[wave * 16 + l16][quad * 8];
    f32x4 sacc[19];
    #pragma unroll
    for (int kt = 0; kt < 19; kt++) {
        const bf16x8 bk = *(const bf16x8*)&u.s.Ks[kt * 16 + l16][quad * 8];
        sacc[kt] = __builtin_amdgcn_mfma_f32_16x16x32_bf16(
            aq, bk, (f32x4){0.f, 0.f, 0.f, 0.f}, 0, 0, 0);
    }

    float inv[4];
    #pragma unroll
    for (int r = 0; r < 4; r++) {
        float m = -1e30f;
        #pragma unroll
        for (int kt = 0; kt < 19; kt++) {
            float s = sacc[kt][r] * scale;
            if (kt == 18 && l16 >= 12) s = -1e30f;
            sacc[kt][r] = s;
            m = fmaxf(m, s);
        }
        m = fmaxf(m, __shfl_xor(m, 1)); m = fmaxf(m, __shfl_xor(m, 2));
        m = fmaxf(m, __shfl_xor(m, 4)); m = fmaxf(m, __shfl_xor(m, 8));
        float sum = 0.f;
        #pragma unroll
        for (int kt = 0; kt < 19; kt++) {
            float p = __expf(sacc[kt][r] - m);
            sacc[kt][r] = p;
            sum += p;
        }
        sum += __shfl_xor(sum, 1); sum += __shfl_xor(sum, 2);
        sum += __shfl_xor(sum, 4); sum += __shfl_xor(sum, 8);
        inv[r] = 1.0f / sum;
    }

    __syncthreads();

    #pragma unroll
    for (int kt = 0; kt < 19; kt++)
        #pragma unroll
        for (int r = 0; r < 4; r++)
            u.Ps[wave][quad * 4 + r][kt * 16 + l16] = f2bf(sacc[kt][r] * inv[r]);
    #pragma unroll
    for (int r = 0; r < 4; r++)
        u.Ps[wave][quad * 4 + r][304 + l16] = 0;

    f32x4 o0 = {0.f, 0.f, 0.f, 0.f}, o1 = {0.f, 0.f, 0.f, 0.f};
    #pragma unroll
    for (int kt = 0; kt < 10; kt++) {
        const bf16x8 ap  = *(const bf16x8*)&u.Ps[wave][l16][kt * 32 + quad * 8];
        const bf16x8 bv0 = *(const bf16x8*)&Vt[l16][kt * 32 + quad * 8];
        const bf16x8 bv1 = *(const bf16x8*)&Vt[16 + l16][kt * 32 + quad * 8];
        o0 = __builtin_amdgcn_mfma_f32_16x16x32_bf16(ap, bv0, o0, 0, 0, 0);
        o1 = __builtin_amdgcn_mfma_f32_16x16x32_bf16(ap, bv1, o1, 0, 0, 0);
    }

    #pragma unroll
    for (int r = 0; r < 4; r++) {
        const int q = q0 + wave * 16 + quad * 4 + r;
        if (q < NQ) {
            float* op = sa + ((long)(b * NQ + q)) * ND + h * 32;
            op[l16]      = o0[r];
            op[16 + l16] = o1[r];
        }
    }
}

// ---------------------------------------------------------------------------
// Residual + LayerNorm (NPART residual partials summed): one wave per row.
// ---------------------------------------------------------------------------
template <int NPART>
__global__ __launch_bounds__(256) void residual_ln(
    const float* __restrict__ a, const float* __restrict__ r,
    const float* __restrict__ gam, const float* __restrict__ bet,
    float* __restrict__ out, long pstride)
{
    const int row  = blockIdx.x * 4 + (threadIdx.x >> 6);
    const int lane = threadIdx.x & 63;
    const long base = (long)row * ND + lane * 4;
    float4 av = *(const float4*)(a + base);
    float4 rv = *(const float4*)(r + base);
    #pragma unroll
    for (int z = 1; z < NPART; z++) {
        float4 pv = *(const float4*)(r + z * pstride + base);
        rv.x += pv.x; rv.y += pv.y; rv.z += pv.z; rv.w += pv.w;
    }
    float x0 = av.x + rv.x, x1 = av.y + rv.y, x2 = av.z + rv.z, x3 = av.w + rv.w;
    float s  = x0 + x1 + x2 + x3;
    float s2 = x0 * x0 + x1 * x1 + x2 * x2 + x3 * x3;
    #pragma unroll
    for (int off = 32; off >= 1; off >>= 1) {
        s  += __shfl_xor(s, off);
        s2 += __shfl_xor(s2, off);
    }
    float mean = s * 0.00390625f;
    float var  = s2 * 0.00390625f - mean * mean;
    float rstd = rsqrtf(var + 1e-5f);
    float4 gv = *(const float4*)(gam + lane * 4);
    float4 bv = *(const float4*)(bet + lane * 4);
    float4 o;
    o.x = (x0 - mean) * rstd * gv.x + bv.x;
    o.y = (x1 - mean) * rstd * gv.y + bv.y;
    o.z = (x2 - mean) * rstd * gv.z + bv.z;
    o.w = (x3 - mean) * rstd * gv.w + bv.w;
    *(float4*)(out + base) = o;
}

// ---------------------------------------------------------------------------
// meta from head-GEMM result res[4800][128].
// ---------------------------------------------------------------------------
__global__ __launch_bounds__(256) void meta_kernel(
    const float* __restrict__ res, float* __restrict__ meta)
{
    const int t   = threadIdx.x;
    const int row = blockIdx.x * 8 + (t >> 5);
    const int s   = t & 31;
    const int h   = s >> 2;
    const float* rp = res + (long)row * 128;
    const float rx = 1.f / (1.f + __expf(-rp[0]));
    const float ry = 1.f / (1.f + __expf(-rp[1]));
    const float offx = rp[2 + 2 * s], offy = rp[3 + 2 * s];
    const float a0 = rp[66 + h * 4 + 0], a1 = rp[66 + h * 4 + 1];
    const float a2 = rp[66 + h * 4 + 2], a3 = rp[66 + h * 4 + 3];
    const float mx = fmaxf(fmaxf(a0, a1), fmaxf(a2, a3));
    const float den = __expf(a0 - mx) + __expf(a1 - mx) +
                      __expf(a2 - mx) + __expf(a3 - mx);
    const float awt = __expf(rp[66 + s] - mx) / den;

    const float lx = fminf(fmaxf(rx + offx, 0.f), 1.f) * (NWG - 1);
    const float ly = fminf(fmaxf(ry + offy, 0.f), 1.f) * (NWG - 1);
    const float fx = floorf(lx), fy = floorf(ly);
    int x0 = (int)fx; x0 = min(max(x0, 0), NWG - 1);
    int y0 = (int)fy; y0 = min(max(y0, 0), NWG - 1);
    const int x1 = min(x0 + 1, NWG - 1);
    const int y1 = min(y0 + 1, NWG - 1);
    const float wx1 = lx - fx, wx0 = 1.f - wx1;
    const float wy1 = ly - fy, wy0 = 1.f - wy1;
    float4 m0, m1;
    m0.x = __int_as_float(y0 * NWG + x0);
    m0.y = __int_as_float(y0 * NWG + x1);
    m0.z = __int_as_float(y1 * NWG + x0);
    m0.w = __int_as_float(y1 * NWG + x1);
    m1.x = awt * wx0 * wy0;
    m1.y = awt * wx1 * wy0;
    m1.z = awt * wx0 * wy1;
    m1.w = awt * wx1 * wy1;
    float* mp = meta + (long)row * 256 + s * 8;
    *(float4*)mp       = m0;
    *(float4*)(mp + 4) = m1;
}

// ---------------------------------------------------------------------------
// Deformable gather: block per (b,q); thread (h = t>>5, d = t&31).
// ---------------------------------------------------------------------------
__global__ __launch_bounds__(256) void deform_gather(
    const float* __restrict__ meta, const unsigned short* __restrict__ vals,
    float* __restrict__ ca)
{
    const int row = blockIdx.x;
    const int b = row / NQ;
    __shared__ float ms[256];
    const int t = threadIdx.x;
    ms[t] = meta[(long)row * 256 + t];
    __syncthreads();
    const int h = t >> 5, d = t & 31;
    const unsigned short* vb = vals + (long)b * NHW * ND + h * 32 + d;
    float acc = 0.f;
    #pragma unroll
    for (int p = 0; p < NP; p++) {
        const float* mp = ms + h * 32 + p * 8;
        const int i00 = __float_as_int(mp[0]);
        const int i01 = __float_as_int(mp[1]);
        const int i10 = __float_as_int(mp[2]);
        const int i11 = __float_as_int(mp[3]);
        acc += mp[4] * bf2f(vb[(long)i00 * ND]);
        acc += mp[5] * bf2f(vb[(long)i01 * ND]);
        acc += mp[6] * bf2f(vb[(long)i10 * ND]);
        acc += mp[7] * bf2f(vb[(long)i11 * ND]);
    }
    ca[(long)row * ND + t] = acc;
}

// ---------------------------------------------------------------------------
extern "C" void kernel_launch(void* const* d_in, const int* in_sizes, int n_in,
                              void* d_out, int out_size, void* d_ws, size_t ws_size,
                              hipStream_t stream)
{
    (void)in_sizes; (void)n_in; (void)out_size; (void)ws_size;
    const float* tgt   = (const float*)d_in[0];
    const float* mem   = (const float*)d_in[1];
    const float* inpw  = (const float*)d_in[2];
    const float* inpb  = (const float*)d_in[3];
    const float* outw  = (const float*)d_in[4];
    const float* outb  = (const float*)d_in[5];
    const float* n1g   = (const float*)d_in[6];
    const float* n1b   = (const float*)d_in[7];
    const float* refw  = (const float*)d_in[8];
    const float* refb  = (const float*)d_in[9];
    const float* offw  = (const float*)d_in[10];
    const float* offb  = (const float*)d_in[11];
    const float* attww = (const float*)d_in[12];
    const float* attwb = (const float*)d_in[13];
    const float* vpw   = (const float*)d_in[14];
    const float* vpb   = (const float*)d_in[15];
    const float* opw   = (const float*)d_in[16];
    const float* opb   = (const float*)d_in[17];
    const float* n2g   = (const float*)d_in[18];
    const float* n2b   = (const float*)d_in[19];
    const float* l1w   = (const float*)d_in[20];
    const float* l1b   = (const float*)d_in[21];
    const float* l2w   = (const float*)d_in[22];
    const float* l2b   = (const float*)d_in[23];
    const float* n3g   = (const float*)d_in[24];
    const float* n3b   = (const float*)d_in[25];
    float* out = (float*)d_out;

    char* p = (char*)d_ws;
    auto alloc = [&](size_t bytes) {
        char* r = p; p += (bytes + 255) & ~(size_t)255; return (void*)r;
    };
    unsigned short* wtIn   = (unsigned short*)alloc(768 * 256 * 2);
    unsigned short* wtOut  = (unsigned short*)alloc(256 * 256 * 2);
    unsigned short* wtVp   = (unsigned short*)alloc(256 * 256 * 2);
    unsigned short* wtOp   = (unsigned short*)alloc(256 * 256 * 2);
    unsigned short* wtL1   = (unsigned short*)alloc(2048 * 256 * 2);
    unsigned short* wtL2   = (unsigned short*)alloc(256 * 2048 * 2);
    unsigned short* wtHead = (unsigned short*)alloc(128 * 256 * 2);
    float*          headb  = (float*)alloc(128 * 4);
    float* qkv  = (float*)alloc((size_t)NROW * 768 * 4);
    float* sa   = (float*)alloc((size_t)NROW * ND * 4);
    float* x1   = (float*)alloc((size_t)NROW * ND * 4);
    float* x2   = (float*)alloc((size_t)NROW * ND * 4);
    float* tmp  = (float*)alloc((size_t)NROW * ND * 4 * 4);   // 4 split-K partials
    float* ca   = (float*)alloc((size_t)NROW * ND * 4);
    float* meta = (float*)alloc((size_t)NROW * 256 * 4);
    void* uni = alloc((size_t)NB * NHW * ND * 2);   // vals bf16 / h1 fp32 alias
    unsigned short* vals = (unsigned short*)uni;
    float* h1 = (float*)uni;
    float* res = qkv;   // head-GEMM result; qkv dead by then

    transpose_cast<<<352, 256, 0, stream>>>(
        inpw, outw, vpw, opw, l1w, l2w,
        wtIn, wtOut, wtVp, wtOp, wtL1, wtL2);
    prep_head<<<129, 256, 0, stream>>>(refw, refb, offw, offb, attww, attwb,
                                       wtHead, headb);

    gemm_bt<0, 0, 1, 64, 256><<<dim3(3, 75), 256, 0, stream>>>(tgt, wtIn, inpb, qkv,
                                                               NROW, 768, 256);
    gemm_vproj_bs<<<250, 512, 0, stream>>>(mem, wtVp, vpb, vals);
    attn_kernel<<<dim3(5, 128), 256, 0, stream>>>(qkv, sa);
    gemm_bt<0, 0, 2, 64, 256><<<dim3(1, 75, 2), 256, 0, stream>>>(sa, wtOut, outb, tmp,
                                                                  NROW, 256, 256);
    residual_ln<2><<<1200, 256, 0, stream>>>(tgt, tmp, n1g, n1b, x1,
                                             (long)NROW * 256);
    gemm_bt<0, 0, 1, 64, 128><<<dim3(1, 75), 256, 0, stream>>>(x1, wtHead, headb, res,
                                                               NROW, 128, 256);
    meta_kernel<<<600, 256, 0, stream>>>(res, meta);
    deform_gather<<<4800, 256, 0, stream>>>(meta, vals, ca);
    gemm_bt<0, 0, 2, 64, 256><<<dim3(1, 75, 2), 256, 0, stream>>>(ca, wtOp, opb, tmp,
                                                                  NROW, 256, 256);
    residual_ln<2><<<1200, 256, 0, stream>>>(x1, tmp, n2g, n2b, x2,
                                             (long)NROW * 256);
    gemm_bt<1, 0, 1, 64, 256><<<dim3(8, 75), 256, 0, stream>>>(x2, wtL1, l1b, h1,
                                                               NROW, 2048, 256);
    gemm_bt<0, 0, 4, 64, 256><<<dim3(1, 75, 4), 256, 0, stream>>>(h1, wtL2, l2b, tmp,
                                                                  NROW, 256, 2048);
    residual_ln<4><<<1200, 256, 0, stream>>>(x2, tmp, n3g, n3b, out,
                                             (long)NROW * 256);
}